// Round 1
// baseline (664.533 us; speedup 1.0000x reference)
//
#include <hip/hip_runtime.h>
#include <math.h>

// Problem constants
#define NB 8           // batch
#define TOPN 4
#define NC 80          // classes
#define NF 1280        // features
#define HW 448         // image H=W
#define OS 14          // conv out spatial
#define NP 196         // OS*OS
#define PATCH (3*42*42)

__device__ __forceinline__ float sigmoidf_(float x) { return 1.0f / (1.0f + expf(-x)); }

// ---------------- K1: global conv (stride 32, pad 1, clip 0..6) + fused spatial mean
// grid (5, 8): x = filter chunk (256 filters), y = batch. 256 threads, 1 filter/thread.
__global__ __launch_bounds__(256) void k1_conv_global(
    const float* __restrict__ in,   // (8,3,448,448)
    const float* __restrict__ fw,   // (1280,3,3,3) flat
    const float* __restrict__ fb,   // (1280)
    float* __restrict__ ga,         // (8,196,1280)
    float* __restrict__ gf)         // (8,1280)
{
  __shared__ float patch[PATCH];
  const int b = blockIdx.y, fc = blockIdx.x, tid = threadIdx.x;
  // stage the 42x42x3 sampled pixel grid (rows/cols 32*o + k - 1, zero pad at -1)
  for (int i = tid; i < PATCH; i += 256) {
    int c = i / 1764, rem = i % 1764, r = rem / 42, cc = rem % 42;
    int row = 32 * (r / 3) + (r % 3) - 1;
    int col = 32 * (cc / 3) + (cc % 3) - 1;
    float v = 0.0f;
    if (row >= 0 && col >= 0)
      v = in[((b * 3 + c) * HW + row) * HW + col];
    patch[i] = v;
  }
  __syncthreads();
  const int f = fc * 256 + tid;
  float w[27];
#pragma unroll
  for (int k = 0; k < 27; ++k) w[k] = fw[f * 27 + k];
  const float bias = fb[f];
  double sum = 0.0;
  for (int oy = 0; oy < OS; ++oy) {
    for (int ox = 0; ox < OS; ++ox) {
      float acc = bias;
#pragma unroll
      for (int c = 0; c < 3; ++c)
#pragma unroll
        for (int ky = 0; ky < 3; ++ky)
#pragma unroll
          for (int kx = 0; kx < 3; ++kx)
            acc += patch[c * 1764 + (oy * 3 + ky) * 42 + (ox * 3 + kx)] * w[c * 9 + ky * 3 + kx];
      acc = fminf(fmaxf(acc, 0.0f), 6.0f);
      ga[((size_t)b * NP + oy * OS + ox) * NF + f] = acc;
      sum += (double)acc;
    }
  }
  gf[b * NF + f] = (float)(sum / 196.0);
}

// ---------------- K2: gs = sigmoid(1x1 conv on gf) -> d_out[0:640]; serial top-4 per batch
__global__ __launch_bounds__(128) void k2_gs_topk(
    const float* __restrict__ gf,   // (8,1280)
    const float* __restrict__ cw,   // (80,1280)
    const float* __restrict__ cb,   // (80)
    float* __restrict__ gs_out,     // d_out
    int* __restrict__ topi)         // (8,4)
{
  __shared__ float gsv[NC];
  const int b = blockIdx.x, tid = threadIdx.x;
  if (tid < NC) {
    const float* g = gf + b * NF;
    const float* w = cw + tid * NF;
    double acc = (double)cb[tid];
    for (int fi = 0; fi < NF; ++fi) acc += (double)g[fi] * (double)w[fi];
    float s = sigmoidf_((float)acc);
    gsv[tid] = s;
    gs_out[b * NC + tid] = s;
  }
  __syncthreads();
  if (tid == 0) {
    bool used[NC];
    for (int i = 0; i < NC; ++i) used[i] = false;
    for (int t = 0; t < TOPN; ++t) {
      int best = 0; float bv = -1.0f;
      for (int i = 0; i < NC; ++i)
        if (!used[i] && gsv[i] > bv) { bv = gsv[i]; best = i; }
      used[best] = true;
      topi[b * TOPN + t] = best;
    }
  }
}

// ---------------- K3: per (b,t): cam(14x14) -> wscore/hscore (448 bilinear max samples)
//                  -> minmax_norm + obj_loc -> integer bounds {y1,y2,x1,x2}
__global__ __launch_bounds__(256) void k3_cam_bounds(
    const float* __restrict__ ga,   // (8,196,1280)
    const float* __restrict__ cw,
    const float* __restrict__ cb,
    const int* __restrict__ topi,
    int* __restrict__ bounds)       // (32,4)
{
  __shared__ float clsw[NF];
  __shared__ float cam[NP];
  __shared__ float wsS[HW];
  __shared__ float hsS[HW];
  __shared__ float vbuf[256 * 15];  // per-thread 14-elem interp buffer, stride 15 (bank-conflict-light)
  const int bt = blockIdx.x, tid = threadIdx.x;
  const int b = bt >> 2;
  const int cls = topi[bt];
  for (int i = tid; i < NF; i += 256) clsw[i] = cw[cls * NF + i];
  __syncthreads();
  if (tid < NP) {
    const float* g = ga + ((size_t)b * NP + tid) * NF;
    double acc = (double)cb[cls];
    for (int fi = 0; fi < NF; ++fi) acc += (double)g[fi] * (double)clsw[fi];
    cam[tid] = sigmoidf_((float)acc);
  }
  __syncthreads();
  const float SC = 13.0f / 447.0f;
  float* cv = vbuf + tid * 15;
  for (int x = tid; x < HW; x += 256) {
    // ---- wscore[x] = max over 448 y-samples of bilinear(cam)[., x]
    {
      float xp = (float)x * SC;
      int x0 = (int)floorf(xp); if (x0 > 13) x0 = 13;
      float wx = xp - (float)x0;
      int x1i = min(x0 + 1, 13);
#pragma unroll
      for (int r = 0; r < OS; ++r)
        cv[r] = cam[r * OS + x0] * (1.0f - wx) + cam[r * OS + x1i] * wx;
      float m = -1e30f;
      for (int j = 0; j < HW; ++j) {
        float yp = (float)j * SC;
        int y0 = (int)floorf(yp); if (y0 > 13) y0 = 13;
        float wy = yp - (float)y0;
        int y1i = min(y0 + 1, 13);
        m = fmaxf(m, cv[y0] * (1.0f - wy) + cv[y1i] * wy);
      }
      wsS[x] = m;
    }
    // ---- hscore[y=x] = max over 448 x-samples
    {
      float yp = (float)x * SC;
      int y0 = (int)floorf(yp); if (y0 > 13) y0 = 13;
      float wy = yp - (float)y0;
      int y1i = min(y0 + 1, 13);
#pragma unroll
      for (int c = 0; c < OS; ++c)
        cv[c] = cam[y0 * OS + c] * (1.0f - wy) + cam[y1i * OS + c] * wy;
      float m = -1e30f;
      for (int j = 0; j < HW; ++j) {
        float xp = (float)j * SC;
        int x0 = (int)floorf(xp); if (x0 > 13) x0 = 13;
        float wx = xp - (float)x0;
        int x1i = min(x0 + 1, 13);
        m = fmaxf(m, cv[x0] * (1.0f - wx) + cv[x1i] * wx);
      }
      hsS[x] = m;
    }
  }
  __syncthreads();
  if (tid < 2) {
    const float* s = (tid == 0) ? wsS : hsS;
    float mn = s[0], mx = s[0];
    for (int i = 1; i < HW; ++i) { mn = fminf(mn, s[i]); mx = fmaxf(mx, s[i]); }
    float rng = mx - mn;
    int first = -1, last = -1;
    for (int i = 0; i < HW; ++i) {
      float nv;
      if (rng > 0.0f) nv = (s[i] - mn) / rng;
      else nv = s[i] / ((mx != 0.0f) ? mx : 1.0f);
      if (nv >= 0.5f) { if (first < 0) first = i; last = i; }
    }
    int lo, hi;
    if (first >= 0) { lo = first; hi = last + 1; }
    else { lo = 56; hi = 392; }               // int(448*0.125), int(448*0.875)
    int need = 56 - (hi - lo); if (need < 0) need = 0;  // minsize = ceil(448*0.125)
    int pad = (need + 1) >> 1;
    lo = lo - pad; if (lo < 0) lo = 0;
    hi = hi + pad; if (hi > HW) hi = HW;
    if (tid == 0) { bounds[bt * 4 + 2] = lo; bounds[bt * 4 + 3] = hi; }  // x1,x2
    else          { bounds[bt * 4 + 0] = lo; bounds[bt * 4 + 1] = hi; }  // y1,y2
  }
}

// ---------------- K4: fused bilinear-crop + conv + clip + spatial mean -> lf (no crop/la materialization)
// grid (5, 32): x = filter chunk, y = (b,t). 256 threads, 1 filter/thread.
__global__ __launch_bounds__(256) void k4_conv_local(
    const float* __restrict__ in,
    const float* __restrict__ fw,
    const float* __restrict__ fb,
    const int* __restrict__ bounds,
    float* __restrict__ lf)         // (32,1280)
{
  __shared__ float patch[PATCH];
  const int bt = blockIdx.y, fc = blockIdx.x, tid = threadIdx.x;
  const int b = bt >> 2;
  const int y1 = bounds[bt * 4 + 0], y2 = bounds[bt * 4 + 1];
  const int x1 = bounds[bt * 4 + 2], x2 = bounds[bt * 4 + 3];
  const float y1f = (float)y1, x1f = (float)x1;
  const float sy = (float)(y2 - 1 - y1) / 447.0f;
  const float sx = (float)(x2 - 1 - x1) / 447.0f;
  const float* img = in + (size_t)b * 3 * HW * HW;
  for (int i = tid; i < PATCH; i += 256) {
    int c = i / 1764, rem = i % 1764, r = rem / 42, cc = rem % 42;
    int yy = 32 * (r / 3) + (r % 3) - 1;   // crop-space row (conv pad -> -1)
    int xx = 32 * (cc / 3) + (cc % 3) - 1;
    float v = 0.0f;
    if (yy >= 0 && xx >= 0) {
      float ys = y1f + (float)yy * sy;
      float xs = x1f + (float)xx * sx;
      float y0 = floorf(ys); if (y0 < 0.0f) y0 = 0.0f; if (y0 > 447.0f) y0 = 447.0f;
      float x0 = floorf(xs); if (x0 < 0.0f) x0 = 0.0f; if (x0 > 447.0f) x0 = 447.0f;
      int y0i = (int)y0, x0i = (int)x0;
      int y1i = min(y0i + 1, HW - 1), x1i = min(x0i + 1, HW - 1);
      float wy = ys - y0, wx = xs - x0;
      const float* ic = img + (size_t)c * HW * HW;
      float a  = ic[y0i * HW + x0i], bb = ic[y0i * HW + x1i];
      float cc2 = ic[y1i * HW + x0i], d  = ic[y1i * HW + x1i];
      float top = a * (1.0f - wx) + bb * wx;
      float bot = cc2 * (1.0f - wx) + d * wx;
      v = top * (1.0f - wy) + bot * wy;
    }
    patch[i] = v;
  }
  __syncthreads();
  const int f = fc * 256 + tid;
  float w[27];
#pragma unroll
  for (int k = 0; k < 27; ++k) w[k] = fw[f * 27 + k];
  const float bias = fb[f];
  double sum = 0.0;
  for (int oy = 0; oy < OS; ++oy) {
    for (int ox = 0; ox < OS; ++ox) {
      float acc = bias;
#pragma unroll
      for (int c = 0; c < 3; ++c)
#pragma unroll
        for (int ky = 0; ky < 3; ++ky)
#pragma unroll
          for (int kx = 0; kx < 3; ++kx)
            acc += patch[c * 1764 + (oy * 3 + ky) * 42 + (ox * 3 + kx)] * w[c * 9 + ky * 3 + kx];
      acc = fminf(fmaxf(acc, 0.0f), 6.0f);
      sum += (double)acc;
    }
  }
  lf[bt * NF + f] = (float)(sum / 196.0);
}

// ---------------- K5: ls = max over t of sigmoid(1x1 conv on lf) -> d_out[640:1280]
__global__ __launch_bounds__(128) void k5_ls(
    const float* __restrict__ lf,   // (32,1280)
    const float* __restrict__ cw,
    const float* __restrict__ cb,
    float* __restrict__ ls_out)     // d_out + 640
{
  const int b = blockIdx.x, tid = threadIdx.x;
  if (tid >= NC) return;
  const float* w = cw + tid * NF;
  float m = -1e30f;
  for (int t = 0; t < TOPN; ++t) {
    const float* l = lf + (size_t)(b * TOPN + t) * NF;
    double acc = (double)cb[tid];
    for (int fi = 0; fi < NF; ++fi) acc += (double)l[fi] * (double)w[fi];
    m = fmaxf(m, sigmoidf_((float)acc));
  }
  ls_out[b * NC + tid] = m;
}

extern "C" void kernel_launch(void* const* d_in, const int* in_sizes, int n_in,
                              void* d_out, int out_size, void* d_ws, size_t ws_size,
                              hipStream_t stream) {
  const float* in = (const float*)d_in[0];   // (8,3,448,448)
  const float* fw = (const float*)d_in[1];   // (1280,3,3,3)
  const float* fb = (const float*)d_in[2];   // (1280)
  const float* cw = (const float*)d_in[3];   // (80,1280,1,1)
  const float* cb = (const float*)d_in[4];   // (80)
  float* out = (float*)d_out;                // gs(640) ++ ls(640)

  float* ga = (float*)d_ws;                  // 8*196*1280
  float* gf = ga + (size_t)NB * NP * NF;     // 8*1280
  float* lf = gf + NB * NF;                  // 32*1280
  int* topi = (int*)(lf + NB * TOPN * NF);   // 32
  int* bounds = topi + NB * TOPN;            // 128

  k1_conv_global<<<dim3(5, NB), 256, 0, stream>>>(in, fw, fb, ga, gf);
  k2_gs_topk<<<NB, 128, 0, stream>>>(gf, cw, cb, out, topi);
  k3_cam_bounds<<<NB * TOPN, 256, 0, stream>>>(ga, cw, cb, topi, bounds);
  k4_conv_local<<<dim3(5, NB * TOPN), 256, 0, stream>>>(in, fw, fb, bounds, lf);
  k5_ls<<<NB, 128, 0, stream>>>(lf, cw, cb, out + 640);
}

// Round 2
// 577.130 us; speedup vs baseline: 1.1514x; 1.1514x over previous
//
#include <hip/hip_runtime.h>
#include <math.h>

// Problem constants
#define NB 8           // batch
#define TOPN 4
#define NC 80          // classes
#define NF 1280        // features
#define HW 448         // image H=W
#define OS 14          // conv out spatial
#define NP 196         // OS*OS
#define PATCH (3*42*42)

__device__ __forceinline__ float sigmoidf_(float x) { return 1.0f / (1.0f + expf(-x)); }

__device__ __forceinline__ double wave_reduce_f64(double v) {
#pragma unroll
  for (int off = 32; off > 0; off >>= 1) v += __shfl_down(v, off);
  return v;
}

// ---------------- K1: global conv (stride 32, pad 1, clip 0..6) + fused spatial mean
// grid (5, 8): x = filter chunk (256 filters), y = batch. 256 threads, 1 filter/thread.
__global__ __launch_bounds__(256) void k1_conv_global(
    const float* __restrict__ in,   // (8,3,448,448)
    const float* __restrict__ fw,   // (1280,3,3,3) flat
    const float* __restrict__ fb,   // (1280)
    float* __restrict__ ga,         // (8,196,1280)
    float* __restrict__ gf)         // (8,1280)
{
  __shared__ float patch[PATCH];
  const int b = blockIdx.y, fc = blockIdx.x, tid = threadIdx.x;
  for (int i = tid; i < PATCH; i += 256) {
    int c = i / 1764, rem = i % 1764, r = rem / 42, cc = rem % 42;
    int row = 32 * (r / 3) + (r % 3) - 1;
    int col = 32 * (cc / 3) + (cc % 3) - 1;
    float v = 0.0f;
    if (row >= 0 && col >= 0)
      v = in[((b * 3 + c) * HW + row) * HW + col];
    patch[i] = v;
  }
  __syncthreads();
  const int f = fc * 256 + tid;
  float w[27];
#pragma unroll
  for (int k = 0; k < 27; ++k) w[k] = fw[f * 27 + k];
  const float bias = fb[f];
  double sum = 0.0;
  for (int oy = 0; oy < OS; ++oy) {
    for (int ox = 0; ox < OS; ++ox) {
      float acc = bias;
#pragma unroll
      for (int c = 0; c < 3; ++c)
#pragma unroll
        for (int ky = 0; ky < 3; ++ky)
#pragma unroll
          for (int kx = 0; kx < 3; ++kx)
            acc += patch[c * 1764 + (oy * 3 + ky) * 42 + (ox * 3 + kx)] * w[c * 9 + ky * 3 + kx];
      acc = fminf(fmaxf(acc, 0.0f), 6.0f);
      ga[((size_t)b * NP + oy * OS + ox) * NF + f] = acc;
      sum += (double)acc;
    }
  }
  gf[b * NF + f] = (float)(sum / 196.0);
}

// ---------------- K2: gs = sigmoid(1x1 conv on gf) -> d_out[0:640]; serial top-4 per batch
// block per b, 256 threads; wave-cooperative coalesced dots.
__global__ __launch_bounds__(256) void k2_gs_topk(
    const float* __restrict__ gf,   // (8,1280)
    const float* __restrict__ cw,   // (80,1280)
    const float* __restrict__ cb,   // (80)
    float* __restrict__ gs_out,     // d_out
    int* __restrict__ topi)         // (8,4)
{
  __shared__ float gfs[NF];
  __shared__ float gsv[NC];
  const int b = blockIdx.x, tid = threadIdx.x;
  for (int i = tid; i < NF; i += 256) gfs[i] = gf[b * NF + i];
  __syncthreads();
  const int wid = tid >> 6, lane = tid & 63;
  for (int j = 0; j < NC / 4; ++j) {
    const int cls = wid * (NC / 4) + j;
    const float* w = cw + (size_t)cls * NF;
    double acc = 0.0;
#pragma unroll
    for (int k = 0; k < NF / 64; ++k) {
      int f = k * 64 + lane;
      acc += (double)w[f] * (double)gfs[f];
    }
    acc = wave_reduce_f64(acc);
    if (lane == 0) {
      float s = sigmoidf_((float)(acc + (double)cb[cls]));
      gsv[cls] = s;
      gs_out[b * NC + cls] = s;
    }
  }
  __syncthreads();
  if (tid == 0) {
    bool used[NC];
    for (int i = 0; i < NC; ++i) used[i] = false;
    for (int t = 0; t < TOPN; ++t) {
      int best = 0; float bv = -1.0f;
      for (int i = 0; i < NC; ++i)
        if (!used[i] && gsv[i] > bv) { bv = gsv[i]; best = i; }
      used[best] = true;
      topi[b * TOPN + t] = best;
    }
  }
}

// ---------------- K3: per (b,t): cam(14x14) -> wscore/hscore (448 bilinear max samples)
//                  -> minmax_norm + obj_loc -> integer bounds {y1,y2,x1,x2}
__global__ __launch_bounds__(256) void k3_cam_bounds(
    const float* __restrict__ ga,   // (8,196,1280)
    const float* __restrict__ cw,
    const float* __restrict__ cb,
    const int* __restrict__ topi,
    int* __restrict__ bounds)       // (32,4)
{
  __shared__ float clsw[NF];
  __shared__ float cam[NP];
  __shared__ float wsS[HW];
  __shared__ float hsS[HW];
  __shared__ float vbuf[256 * 15];  // per-thread 14-elem interp buffer, stride 15
  const int bt = blockIdx.x, tid = threadIdx.x;
  const int b = bt >> 2;
  const int cls = topi[bt];
  for (int i = tid; i < NF; i += 256) clsw[i] = cw[cls * NF + i];
  __syncthreads();
  // cam: 196 dots, wave-cooperative (coalesced ga reads, f64 tree reduce)
  const int wid = tid >> 6, lane = tid & 63;
  const double bias = (double)cb[cls];
  for (int i = 0; i < NP / 4; ++i) {
    const int p = wid * (NP / 4) + i;
    const float* g = ga + ((size_t)b * NP + p) * NF;
    double acc = 0.0;
#pragma unroll
    for (int k = 0; k < NF / 64; ++k) {
      int f = k * 64 + lane;
      acc += (double)g[f] * (double)clsw[f];
    }
    acc = wave_reduce_f64(acc);
    if (lane == 0) cam[p] = sigmoidf_((float)(acc + bias));
  }
  __syncthreads();
  const float SC = 13.0f / 447.0f;
  float* cv = vbuf + tid * 15;
  for (int x = tid; x < HW; x += 256) {
    // ---- wscore[x] = max over 448 y-samples of bilinear(cam)[., x]
    {
      float xp = (float)x * SC;
      int x0 = (int)floorf(xp); if (x0 > 13) x0 = 13;
      float wx = xp - (float)x0;
      int x1i = min(x0 + 1, 13);
#pragma unroll
      for (int r = 0; r < OS; ++r)
        cv[r] = cam[r * OS + x0] * (1.0f - wx) + cam[r * OS + x1i] * wx;
      float m = -1e30f;
      for (int j = 0; j < HW; ++j) {
        float yp = (float)j * SC;
        int y0 = (int)floorf(yp); if (y0 > 13) y0 = 13;
        float wy = yp - (float)y0;
        int y1i = min(y0 + 1, 13);
        m = fmaxf(m, cv[y0] * (1.0f - wy) + cv[y1i] * wy);
      }
      wsS[x] = m;
    }
    // ---- hscore[y=x] = max over 448 x-samples
    {
      float yp = (float)x * SC;
      int y0 = (int)floorf(yp); if (y0 > 13) y0 = 13;
      float wy = yp - (float)y0;
      int y1i = min(y0 + 1, 13);
#pragma unroll
      for (int c = 0; c < OS; ++c)
        cv[c] = cam[y0 * OS + c] * (1.0f - wy) + cam[y1i * OS + c] * wy;
      float m = -1e30f;
      for (int j = 0; j < HW; ++j) {
        float xp = (float)j * SC;
        int x0 = (int)floorf(xp); if (x0 > 13) x0 = 13;
        float wx = xp - (float)x0;
        int x1i = min(x0 + 1, 13);
        m = fmaxf(m, cv[x0] * (1.0f - wx) + cv[x1i] * wx);
      }
      hsS[x] = m;
    }
  }
  __syncthreads();
  if (tid < 2) {
    const float* s = (tid == 0) ? wsS : hsS;
    float mn = s[0], mx = s[0];
    for (int i = 1; i < HW; ++i) { mn = fminf(mn, s[i]); mx = fmaxf(mx, s[i]); }
    float rng = mx - mn;
    int first = -1, last = -1;
    for (int i = 0; i < HW; ++i) {
      float nv;
      if (rng > 0.0f) nv = (s[i] - mn) / rng;
      else nv = s[i] / ((mx != 0.0f) ? mx : 1.0f);
      if (nv >= 0.5f) { if (first < 0) first = i; last = i; }
    }
    int lo, hi;
    if (first >= 0) { lo = first; hi = last + 1; }
    else { lo = 56; hi = 392; }               // int(448*0.125), int(448*0.875)
    int need = 56 - (hi - lo); if (need < 0) need = 0;  // minsize = ceil(448*0.125)
    int pad = (need + 1) >> 1;
    lo = lo - pad; if (lo < 0) lo = 0;
    hi = hi + pad; if (hi > HW) hi = HW;
    if (tid == 0) { bounds[bt * 4 + 2] = lo; bounds[bt * 4 + 3] = hi; }  // x1,x2
    else          { bounds[bt * 4 + 0] = lo; bounds[bt * 4 + 1] = hi; }  // y1,y2
  }
}

// ---------------- K4: fused bilinear-crop + conv + clip + spatial mean -> lf
// grid (5, 32): x = filter chunk, y = (b,t). 256 threads, 1 filter/thread.
__global__ __launch_bounds__(256) void k4_conv_local(
    const float* __restrict__ in,
    const float* __restrict__ fw,
    const float* __restrict__ fb,
    const int* __restrict__ bounds,
    float* __restrict__ lf)         // (32,1280)
{
  __shared__ float patch[PATCH];
  const int bt = blockIdx.y, fc = blockIdx.x, tid = threadIdx.x;
  const int b = bt >> 2;
  const int y1 = bounds[bt * 4 + 0], y2 = bounds[bt * 4 + 1];
  const int x1 = bounds[bt * 4 + 2], x2 = bounds[bt * 4 + 3];
  const float y1f = (float)y1, x1f = (float)x1;
  const float sy = (float)(y2 - 1 - y1) / 447.0f;
  const float sx = (float)(x2 - 1 - x1) / 447.0f;
  const float* img = in + (size_t)b * 3 * HW * HW;
  for (int i = tid; i < PATCH; i += 256) {
    int c = i / 1764, rem = i % 1764, r = rem / 42, cc = rem % 42;
    int yy = 32 * (r / 3) + (r % 3) - 1;   // crop-space row (conv pad -> -1)
    int xx = 32 * (cc / 3) + (cc % 3) - 1;
    float v = 0.0f;
    if (yy >= 0 && xx >= 0) {
      float ys = y1f + (float)yy * sy;
      float xs = x1f + (float)xx * sx;
      float y0 = floorf(ys); if (y0 < 0.0f) y0 = 0.0f; if (y0 > 447.0f) y0 = 447.0f;
      float x0 = floorf(xs); if (x0 < 0.0f) x0 = 0.0f; if (x0 > 447.0f) x0 = 447.0f;
      int y0i = (int)y0, x0i = (int)x0;
      int y1i = min(y0i + 1, HW - 1), x1i = min(x0i + 1, HW - 1);
      float wy = ys - y0, wx = xs - x0;
      const float* ic = img + (size_t)c * HW * HW;
      float a  = ic[y0i * HW + x0i], bb = ic[y0i * HW + x1i];
      float cc2 = ic[y1i * HW + x0i], d  = ic[y1i * HW + x1i];
      float top = a * (1.0f - wx) + bb * wx;
      float bot = cc2 * (1.0f - wx) + d * wx;
      v = top * (1.0f - wy) + bot * wy;
    }
    patch[i] = v;
  }
  __syncthreads();
  const int f = fc * 256 + tid;
  float w[27];
#pragma unroll
  for (int k = 0; k < 27; ++k) w[k] = fw[f * 27 + k];
  const float bias = fb[f];
  double sum = 0.0;
  for (int oy = 0; oy < OS; ++oy) {
    for (int ox = 0; ox < OS; ++ox) {
      float acc = bias;
#pragma unroll
      for (int c = 0; c < 3; ++c)
#pragma unroll
        for (int ky = 0; ky < 3; ++ky)
#pragma unroll
          for (int kx = 0; kx < 3; ++kx)
            acc += patch[c * 1764 + (oy * 3 + ky) * 42 + (ox * 3 + kx)] * w[c * 9 + ky * 3 + kx];
      acc = fminf(fmaxf(acc, 0.0f), 6.0f);
      sum += (double)acc;
    }
  }
  lf[bt * NF + f] = (float)(sum / 196.0);
}

// ---------------- K5: ls = max over t of sigmoid(1x1 conv on lf) -> d_out[640:1280]
// block per b, 256 threads; stage 4 lf rows in LDS; one cw pass covers all 4 t.
__global__ __launch_bounds__(256) void k5_ls(
    const float* __restrict__ lf,   // (32,1280)
    const float* __restrict__ cw,
    const float* __restrict__ cb,
    float* __restrict__ ls_out)     // d_out + 640
{
  __shared__ float lfs[TOPN * NF];  // 20 KB
  const int b = blockIdx.x, tid = threadIdx.x;
  for (int i = tid; i < TOPN * NF; i += 256) lfs[i] = lf[(size_t)b * TOPN * NF + i];
  __syncthreads();
  const int wid = tid >> 6, lane = tid & 63;
  for (int j = 0; j < NC / 4; ++j) {
    const int cls = wid * (NC / 4) + j;
    const float* w = cw + (size_t)cls * NF;
    double a0 = 0.0, a1 = 0.0, a2 = 0.0, a3 = 0.0;
#pragma unroll
    for (int k = 0; k < NF / 64; ++k) {
      int f = k * 64 + lane;
      double wv = (double)w[f];
      a0 += wv * (double)lfs[0 * NF + f];
      a1 += wv * (double)lfs[1 * NF + f];
      a2 += wv * (double)lfs[2 * NF + f];
      a3 += wv * (double)lfs[3 * NF + f];
    }
    a0 = wave_reduce_f64(a0);
    a1 = wave_reduce_f64(a1);
    a2 = wave_reduce_f64(a2);
    a3 = wave_reduce_f64(a3);
    if (lane == 0) {
      double bias = (double)cb[cls];
      float m = sigmoidf_((float)(a0 + bias));
      m = fmaxf(m, sigmoidf_((float)(a1 + bias)));
      m = fmaxf(m, sigmoidf_((float)(a2 + bias)));
      m = fmaxf(m, sigmoidf_((float)(a3 + bias)));
      ls_out[b * NC + cls] = m;
    }
  }
}

extern "C" void kernel_launch(void* const* d_in, const int* in_sizes, int n_in,
                              void* d_out, int out_size, void* d_ws, size_t ws_size,
                              hipStream_t stream) {
  const float* in = (const float*)d_in[0];   // (8,3,448,448)
  const float* fw = (const float*)d_in[1];   // (1280,3,3,3)
  const float* fb = (const float*)d_in[2];   // (1280)
  const float* cw = (const float*)d_in[3];   // (80,1280,1,1)
  const float* cb = (const float*)d_in[4];   // (80)
  float* out = (float*)d_out;                // gs(640) ++ ls(640)

  float* ga = (float*)d_ws;                  // 8*196*1280
  float* gf = ga + (size_t)NB * NP * NF;     // 8*1280
  float* lf = gf + NB * NF;                  // 32*1280
  int* topi = (int*)(lf + NB * TOPN * NF);   // 32
  int* bounds = topi + NB * TOPN;            // 128

  k1_conv_global<<<dim3(5, NB), 256, 0, stream>>>(in, fw, fb, ga, gf);
  k2_gs_topk<<<NB, 256, 0, stream>>>(gf, cw, cb, out, topi);
  k3_cam_bounds<<<NB * TOPN, 256, 0, stream>>>(ga, cw, cb, topi, bounds);
  k4_conv_local<<<dim3(5, NB * TOPN), 256, 0, stream>>>(in, fw, fb, bounds, lf);
  k5_ls<<<NB, 256, 0, stream>>>(lf, cw, cb, out + 640);
}

// Round 3
// 476.611 us; speedup vs baseline: 1.3943x; 1.2109x over previous
//
#include <hip/hip_runtime.h>
#include <math.h>

// Problem constants
#define NB 8           // batch
#define TOPN 4
#define NC 80          // classes
#define NF 1280        // features
#define HW 448         // image H=W
#define OS 14          // conv out spatial
#define NP 196         // OS*OS
#define PATCH (3*42*42)

__device__ __forceinline__ float sigmoidf_(float x) { return 1.0f / (1.0f + expf(-x)); }

__device__ __forceinline__ double wave_reduce_f64(double v) {
#pragma unroll
  for (int off = 32; off > 0; off >>= 1) v += __shfl_down(v, off);
  return v;
}

// ---------------- K1: global conv (stride 32, pad 1, clip 0..6) + fused spatial mean
// grid (5, 8): x = filter chunk (256 filters), y = batch. 256 threads, 1 filter/thread.
__global__ __launch_bounds__(256) void k1_conv_global(
    const float* __restrict__ in,   // (8,3,448,448)
    const float* __restrict__ fw,   // (1280,3,3,3) flat
    const float* __restrict__ fb,   // (1280)
    float* __restrict__ ga,         // (8,196,1280)
    float* __restrict__ gf)         // (8,1280)
{
  __shared__ float patch[PATCH];
  const int b = blockIdx.y, fc = blockIdx.x, tid = threadIdx.x;
  for (int i = tid; i < PATCH; i += 256) {
    int c = i / 1764, rem = i % 1764, r = rem / 42, cc = rem % 42;
    int row = 32 * (r / 3) + (r % 3) - 1;
    int col = 32 * (cc / 3) + (cc % 3) - 1;
    float v = 0.0f;
    if (row >= 0 && col >= 0)
      v = in[((b * 3 + c) * HW + row) * HW + col];
    patch[i] = v;
  }
  __syncthreads();
  const int f = fc * 256 + tid;
  float w[27];
#pragma unroll
  for (int k = 0; k < 27; ++k) w[k] = fw[f * 27 + k];
  const float bias = fb[f];
  double sum = 0.0;
  for (int oy = 0; oy < OS; ++oy) {
#pragma unroll 4
    for (int ox = 0; ox < OS; ++ox) {   // unroll -> 4 independent fmac chains (same per-position op order)
      float acc = bias;
#pragma unroll
      for (int c = 0; c < 3; ++c)
#pragma unroll
        for (int ky = 0; ky < 3; ++ky)
#pragma unroll
          for (int kx = 0; kx < 3; ++kx)
            acc += patch[c * 1764 + (oy * 3 + ky) * 42 + (ox * 3 + kx)] * w[c * 9 + ky * 3 + kx];
      acc = fminf(fmaxf(acc, 0.0f), 6.0f);
      ga[((size_t)b * NP + oy * OS + ox) * NF + f] = acc;
      sum += (double)acc;
    }
  }
  gf[b * NF + f] = (float)(sum / 196.0);
}

// ---------------- K2: gs = sigmoid(1x1 conv on gf) -> d_out[0:640]; serial top-4 per batch
__global__ __launch_bounds__(256) void k2_gs_topk(
    const float* __restrict__ gf,   // (8,1280)
    const float* __restrict__ cw,   // (80,1280)
    const float* __restrict__ cb,   // (80)
    float* __restrict__ gs_out,     // d_out
    int* __restrict__ topi)         // (8,4)
{
  __shared__ float gfs[NF];
  __shared__ float gsv[NC];
  const int b = blockIdx.x, tid = threadIdx.x;
  for (int i = tid; i < NF; i += 256) gfs[i] = gf[b * NF + i];
  __syncthreads();
  const int wid = tid >> 6, lane = tid & 63;
  for (int j = 0; j < NC / 8; ++j) {          // 2 classes per iter for ILP
    const int cls0 = wid * (NC / 4) + 2 * j;
    const int cls1 = cls0 + 1;
    const float* w0 = cw + (size_t)cls0 * NF;
    const float* w1 = cw + (size_t)cls1 * NF;
    double a0 = 0.0, a1 = 0.0;
#pragma unroll
    for (int k = 0; k < NF / 64; ++k) {
      int f = k * 64 + lane;
      double g = (double)gfs[f];
      a0 += (double)w0[f] * g;
      a1 += (double)w1[f] * g;
    }
    a0 = wave_reduce_f64(a0);
    a1 = wave_reduce_f64(a1);
    if (lane == 0) {
      float s0 = sigmoidf_((float)(a0 + (double)cb[cls0]));
      float s1 = sigmoidf_((float)(a1 + (double)cb[cls1]));
      gsv[cls0] = s0; gs_out[b * NC + cls0] = s0;
      gsv[cls1] = s1; gs_out[b * NC + cls1] = s1;
    }
  }
  __syncthreads();
  if (tid == 0) {
    bool used[NC];
    for (int i = 0; i < NC; ++i) used[i] = false;
    for (int t = 0; t < TOPN; ++t) {
      int best = 0; float bv = -1.0f;
      for (int i = 0; i < NC; ++i)
        if (!used[i] && gsv[i] > bv) { bv = gsv[i]; best = i; }
      used[best] = true;
      topi[b * TOPN + t] = best;
    }
  }
}

// ---------------- K3: per (b,t): cam(14x14) -> wscore/hscore via segment-max
//                  -> minmax_norm + obj_loc -> integer bounds {y1,y2,x1,x2}
__global__ __launch_bounds__(256) void k3_cam_bounds(
    const float* __restrict__ ga,   // (8,196,1280)
    const float* __restrict__ cw,
    const float* __restrict__ cb,
    const int* __restrict__ topi,
    int* __restrict__ bounds)       // (32,4)
{
  __shared__ float clsw[NF];
  __shared__ float cam[NP];
  __shared__ float wsS[HW];
  __shared__ float hsS[HW];
  __shared__ int jlo[OS], jhi[OS];
  const int tid = threadIdx.x;
  // XCD swizzle: 4 blocks of the same batch b land on the same XCD (share ga slice in L2)
  const int bt = ((int)blockIdx.x % 8) * 4 + (int)blockIdx.x / 8;
  const int b = bt >> 2;
  const int cls = topi[bt];
  const float SC = 13.0f / 447.0f;

  if (tid < OS) { jlo[tid] = 1 << 30; jhi[tid] = -1; }
  for (int i = tid; i < NF; i += 256) clsw[i] = cw[cls * NF + i];
  __syncthreads();
  // per-segment extreme sample indices (identical floor/clamp math as the sampling)
  for (int j = tid; j < HW; j += 256) {
    float yp = (float)j * SC;
    int y0 = (int)floorf(yp); if (y0 > 13) y0 = 13;
    atomicMin(&jlo[y0], j);
    atomicMax(&jhi[y0], j);
  }

  // cam: 196 dots, wave-cooperative, 2 positions in flight
  const int wid = tid >> 6, lane = tid & 63;
  const double bias = (double)cb[cls];
  const int base = wid * 49;
  for (int i = 0; i < 48; i += 2) {
    const int p0 = base + i, p1 = base + i + 1;
    const float* g0 = ga + ((size_t)b * NP + p0) * NF;
    const float* g1 = ga + ((size_t)b * NP + p1) * NF;
    double a0 = 0.0, a1 = 0.0;
#pragma unroll
    for (int k = 0; k < NF / 64; ++k) {
      int f = k * 64 + lane;
      double wv = (double)clsw[f];
      a0 += (double)g0[f] * wv;
      a1 += (double)g1[f] * wv;
    }
    a0 = wave_reduce_f64(a0);
    a1 = wave_reduce_f64(a1);
    if (lane == 0) {
      cam[p0] = sigmoidf_((float)(a0 + bias));
      cam[p1] = sigmoidf_((float)(a1 + bias));
    }
  }
  { // tail position
    const int p = base + 48;
    const float* g = ga + ((size_t)b * NP + p) * NF;
    double a = 0.0;
#pragma unroll
    for (int k = 0; k < NF / 64; ++k) {
      int f = k * 64 + lane;
      a += (double)g[f] * (double)clsw[f];
    }
    a = wave_reduce_f64(a);
    if (lane == 0) cam[p] = sigmoidf_((float)(a + bias));
  }
  __syncthreads();

  // phase B: per output column/row, piecewise-linear segment max (2 evals/segment)
  for (int x = tid; x < HW; x += 256) {
    float xp = (float)x * SC;
    int x0 = (int)floorf(xp); if (x0 > 13) x0 = 13;
    float wx = xp - (float)x0;
    int x1i = min(x0 + 1, 13);
    // wscore[x]: interp along x first -> cv[r], then max over y-samples
    {
      float cv[OS];
#pragma unroll
      for (int r = 0; r < OS; ++r)
        cv[r] = cam[r * OS + x0] * (1.0f - wx) + cam[r * OS + x1i] * wx;
      float m = -1e30f;
#pragma unroll
      for (int r = 0; r < OS; ++r) {
        int jl = jlo[r], jh = jhi[r];
        if (jl <= jh) {
          const int rn = (r + 1 < OS) ? r + 1 : OS - 1;
          float yp1 = (float)jl * SC; float wy1 = yp1 - (float)r;
          float yp2 = (float)jh * SC; float wy2 = yp2 - (float)r;
          float v1 = cv[r] * (1.0f - wy1) + cv[rn] * wy1;
          float v2 = cv[r] * (1.0f - wy2) + cv[rn] * wy2;
          m = fmaxf(m, fmaxf(v1, v2));
        }
      }
      wsS[x] = m;
    }
    // hscore[y=x]: interp along y first -> cv[c], then max over x-samples
    {
      float cv[OS];
#pragma unroll
      for (int c = 0; c < OS; ++c)
        cv[c] = cam[x0 * OS + c] * (1.0f - wx) + cam[x1i * OS + c] * wx;
      float m = -1e30f;
#pragma unroll
      for (int r = 0; r < OS; ++r) {
        int jl = jlo[r], jh = jhi[r];
        if (jl <= jh) {
          const int rn = (r + 1 < OS) ? r + 1 : OS - 1;
          float xp1 = (float)jl * SC; float w1 = xp1 - (float)r;
          float xp2 = (float)jh * SC; float w2 = xp2 - (float)r;
          float v1 = cv[r] * (1.0f - w1) + cv[rn] * w1;
          float v2 = cv[r] * (1.0f - w2) + cv[rn] * w2;
          m = fmaxf(m, fmaxf(v1, v2));
        }
      }
      hsS[x] = m;
    }
  }
  __syncthreads();

  // phase C: parallel minmax_norm + obj_loc. wave0 -> wscore(x bounds), wave1 -> hscore(y bounds)
  if (wid < 2) {
    const float* s = (wid == 0) ? wsS : hsS;
    float v[7];
    float mn = 1e30f, mx = -1e30f;
#pragma unroll
    for (int q = 0; q < 7; ++q) {
      v[q] = s[lane + 64 * q];
      mn = fminf(mn, v[q]); mx = fmaxf(mx, v[q]);
    }
#pragma unroll
    for (int off = 32; off > 0; off >>= 1) {
      mn = fminf(mn, __shfl_down(mn, off));
      mx = fmaxf(mx, __shfl_down(mx, off));
    }
    mn = __shfl(mn, 0); mx = __shfl(mx, 0);
    float rng = mx - mn;
    float dnm = (mx != 0.0f) ? mx : 1.0f;
    int firstL = 1 << 30, lastL = -1;
#pragma unroll
    for (int q = 0; q < 7; ++q) {
      float nv = (rng > 0.0f) ? (v[q] - mn) / rng : v[q] / dnm;
      if (nv >= 0.5f) {
        int idx = lane + 64 * q;
        firstL = min(firstL, idx);
        lastL = max(lastL, idx);
      }
    }
#pragma unroll
    for (int off = 32; off > 0; off >>= 1) {
      firstL = min(firstL, __shfl_down(firstL, off));
      lastL = max(lastL, __shfl_down(lastL, off));
    }
    if (lane == 0) {
      int lo, hi;
      if (lastL >= 0) { lo = firstL; hi = lastL + 1; }
      else { lo = 56; hi = 392; }             // int(448*0.125), int(448*0.875)
      int need = 56 - (hi - lo); if (need < 0) need = 0;
      int pad = (need + 1) >> 1;
      lo = lo - pad; if (lo < 0) lo = 0;
      hi = hi + pad; if (hi > HW) hi = HW;
      if (wid == 0) { bounds[bt * 4 + 2] = lo; bounds[bt * 4 + 3] = hi; }  // x1,x2
      else          { bounds[bt * 4 + 0] = lo; bounds[bt * 4 + 1] = hi; }  // y1,y2
    }
  }
}

// ---------------- K4: fused bilinear-crop + conv + clip + spatial mean -> lf
// grid (5, 32): x = filter chunk, y = (b,t). 256 threads, 1 filter/thread.
__global__ __launch_bounds__(256) void k4_conv_local(
    const float* __restrict__ in,
    const float* __restrict__ fw,
    const float* __restrict__ fb,
    const int* __restrict__ bounds,
    float* __restrict__ lf)         // (32,1280)
{
  __shared__ float patch[PATCH];
  const int bt = blockIdx.y, fc = blockIdx.x, tid = threadIdx.x;
  const int b = bt >> 2;
  const int y1 = bounds[bt * 4 + 0], y2 = bounds[bt * 4 + 1];
  const int x1 = bounds[bt * 4 + 2], x2 = bounds[bt * 4 + 3];
  const float y1f = (float)y1, x1f = (float)x1;
  const float sy = (float)(y2 - 1 - y1) / 447.0f;
  const float sx = (float)(x2 - 1 - x1) / 447.0f;
  const float* img = in + (size_t)b * 3 * HW * HW;
  for (int i = tid; i < PATCH; i += 256) {
    int c = i / 1764, rem = i % 1764, r = rem / 42, cc = rem % 42;
    int yy = 32 * (r / 3) + (r % 3) - 1;   // crop-space row (conv pad -> -1)
    int xx = 32 * (cc / 3) + (cc % 3) - 1;
    float v = 0.0f;
    if (yy >= 0 && xx >= 0) {
      float ys = y1f + (float)yy * sy;
      float xs = x1f + (float)xx * sx;
      float y0 = floorf(ys); if (y0 < 0.0f) y0 = 0.0f; if (y0 > 447.0f) y0 = 447.0f;
      float x0 = floorf(xs); if (x0 < 0.0f) x0 = 0.0f; if (x0 > 447.0f) x0 = 447.0f;
      int y0i = (int)y0, x0i = (int)x0;
      int y1i = min(y0i + 1, HW - 1), x1i = min(x0i + 1, HW - 1);
      float wy = ys - y0, wx = xs - x0;
      const float* ic = img + (size_t)c * HW * HW;
      float a  = ic[y0i * HW + x0i], bb = ic[y0i * HW + x1i];
      float cc2 = ic[y1i * HW + x0i], d  = ic[y1i * HW + x1i];
      float top = a * (1.0f - wx) + bb * wx;
      float bot = cc2 * (1.0f - wx) + d * wx;
      v = top * (1.0f - wy) + bot * wy;
    }
    patch[i] = v;
  }
  __syncthreads();
  const int f = fc * 256 + tid;
  float w[27];
#pragma unroll
  for (int k = 0; k < 27; ++k) w[k] = fw[f * 27 + k];
  const float bias = fb[f];
  double sum = 0.0;
  for (int oy = 0; oy < OS; ++oy) {
#pragma unroll 4
    for (int ox = 0; ox < OS; ++ox) {
      float acc = bias;
#pragma unroll
      for (int c = 0; c < 3; ++c)
#pragma unroll
        for (int ky = 0; ky < 3; ++ky)
#pragma unroll
          for (int kx = 0; kx < 3; ++kx)
            acc += patch[c * 1764 + (oy * 3 + ky) * 42 + (ox * 3 + kx)] * w[c * 9 + ky * 3 + kx];
      acc = fminf(fmaxf(acc, 0.0f), 6.0f);
      sum += (double)acc;
    }
  }
  lf[bt * NF + f] = (float)(sum / 196.0);
}

// ---------------- K5: ls = max over t of sigmoid(1x1 conv on lf) -> d_out[640:1280]
__global__ __launch_bounds__(256) void k5_ls(
    const float* __restrict__ lf,   // (32,1280)
    const float* __restrict__ cw,
    const float* __restrict__ cb,
    float* __restrict__ ls_out)     // d_out + 640
{
  __shared__ float lfs[TOPN * NF];  // 20 KB
  const int b = blockIdx.x, tid = threadIdx.x;
  for (int i = tid; i < TOPN * NF; i += 256) lfs[i] = lf[(size_t)b * TOPN * NF + i];
  __syncthreads();
  const int wid = tid >> 6, lane = tid & 63;
  for (int j = 0; j < NC / 4; ++j) {
    const int cls = wid * (NC / 4) + j;
    const float* w = cw + (size_t)cls * NF;
    double a0 = 0.0, a1 = 0.0, a2 = 0.0, a3 = 0.0;
#pragma unroll
    for (int k = 0; k < NF / 64; ++k) {
      int f = k * 64 + lane;
      double wv = (double)w[f];
      a0 += wv * (double)lfs[0 * NF + f];
      a1 += wv * (double)lfs[1 * NF + f];
      a2 += wv * (double)lfs[2 * NF + f];
      a3 += wv * (double)lfs[3 * NF + f];
    }
    a0 = wave_reduce_f64(a0);
    a1 = wave_reduce_f64(a1);
    a2 = wave_reduce_f64(a2);
    a3 = wave_reduce_f64(a3);
    if (lane == 0) {
      double bias = (double)cb[cls];
      float m = sigmoidf_((float)(a0 + bias));
      m = fmaxf(m, sigmoidf_((float)(a1 + bias)));
      m = fmaxf(m, sigmoidf_((float)(a2 + bias)));
      m = fmaxf(m, sigmoidf_((float)(a3 + bias)));
      ls_out[b * NC + cls] = m;
    }
  }
}

extern "C" void kernel_launch(void* const* d_in, const int* in_sizes, int n_in,
                              void* d_out, int out_size, void* d_ws, size_t ws_size,
                              hipStream_t stream) {
  const float* in = (const float*)d_in[0];   // (8,3,448,448)
  const float* fw = (const float*)d_in[1];   // (1280,3,3,3)
  const float* fb = (const float*)d_in[2];   // (1280)
  const float* cw = (const float*)d_in[3];   // (80,1280,1,1)
  const float* cb = (const float*)d_in[4];   // (80)
  float* out = (float*)d_out;                // gs(640) ++ ls(640)

  float* ga = (float*)d_ws;                  // 8*196*1280
  float* gf = ga + (size_t)NB * NP * NF;     // 8*1280
  float* lf = gf + NB * NF;                  // 32*1280
  int* topi = (int*)(lf + NB * TOPN * NF);   // 32
  int* bounds = topi + NB * TOPN;            // 128

  k1_conv_global<<<dim3(5, NB), 256, 0, stream>>>(in, fw, fb, ga, gf);
  k2_gs_topk<<<NB, 256, 0, stream>>>(gf, cw, cb, out, topi);
  k3_cam_bounds<<<NB * TOPN, 256, 0, stream>>>(ga, cw, cb, topi, bounds);
  k4_conv_local<<<dim3(5, NB * TOPN), 256, 0, stream>>>(in, fw, fb, bounds, lf);
  k5_ls<<<NB, 256, 0, stream>>>(lf, cw, cb, out + 640);
}

// Round 5
// 223.461 us; speedup vs baseline: 2.9738x; 2.1329x over previous
//
#include <hip/hip_runtime.h>
#include <math.h>

// Problem constants
#define NB 8           // batch
#define TOPN 4
#define NC 80          // classes
#define NF 1280        // features
#define HW 448         // image H=W
#define OS 14          // conv out spatial
#define NP 196         // OS*OS
#define NPCH 49        // positions per z-chunk (NP/4)
#define PATCH (3*42*42)

__device__ __forceinline__ float sigmoidf_(float x) { return 1.0f / (1.0f + expf(-x)); }

__device__ __forceinline__ double wave_reduce_f64(double v) {
#pragma unroll
  for (int off = 32; off > 0; off >>= 1) v += __shfl_down(v, off);
  return v;
}

// ---------------- K1: global conv (stride 32, pad 1, clip 0..6), position-split 4x.
// grid (5, 8, 4): x = filter chunk (256 filters), y = batch, z = 49-position chunk.
// Writes ga (full activations) and f64 partial spatial sums gfp[pz][b][f].
__global__ __launch_bounds__(256) void k1_conv_global(
    const float* __restrict__ in,   // (8,3,448,448)
    const float* __restrict__ fw,   // (1280,3,3,3) flat
    const float* __restrict__ fb,   // (1280)
    float* __restrict__ ga,         // (8,196,1280)
    double* __restrict__ gfp)       // (4,8,1280) partial sums
{
  __shared__ float patch[PATCH];
  const int b = blockIdx.y, fc = blockIdx.x, pz = blockIdx.z, tid = threadIdx.x;
  for (int i = tid; i < PATCH; i += 256) {
    int c = i / 1764, rem = i % 1764, r = rem / 42, cc = rem % 42;
    int row = 32 * (r / 3) + (r % 3) - 1;
    int col = 32 * (cc / 3) + (cc % 3) - 1;
    float v = 0.0f;
    if (row >= 0 && col >= 0)
      v = in[((b * 3 + c) * HW + row) * HW + col];
    patch[i] = v;
  }
  __syncthreads();
  const int f = fc * 256 + tid;
  float w[27];
#pragma unroll
  for (int k = 0; k < 27; ++k) w[k] = fw[f * 27 + k];
  const float bias = fb[f];
  double sum = 0.0;
#pragma unroll 7
  for (int pi = 0; pi < NPCH; ++pi) {
    const int p = pz * NPCH + pi;
    const int oy = p / OS, ox = p % OS;
    float acc = bias;
#pragma unroll
    for (int c = 0; c < 3; ++c)
#pragma unroll
      for (int ky = 0; ky < 3; ++ky)
#pragma unroll
        for (int kx = 0; kx < 3; ++kx)
          acc += patch[c * 1764 + (oy * 3 + ky) * 42 + (ox * 3 + kx)] * w[c * 9 + ky * 3 + kx];
    acc = fminf(fmaxf(acc, 0.0f), 6.0f);
    ga[((size_t)b * NP + p) * NF + f] = acc;
    sum += (double)acc;
  }
  gfp[((size_t)pz * NB + b) * NF + f] = sum;
}

// ---------------- K2a: gs = sigmoid(1x1 conv on gf). One wave per (b, cls).
// grid (80, 8), 64 threads. Combines the 4 f64 partial sums -> f32 gf inline.
__global__ __launch_bounds__(64) void k2a_gs(
    const double* __restrict__ gfp, // (4,8,1280)
    const float* __restrict__ cw,   // (80,1280)
    const float* __restrict__ cb,   // (80)
    float* __restrict__ gs_out)     // d_out (8,80)
{
  const int cls = blockIdx.x, b = blockIdx.y, lane = threadIdx.x;
  const float* w = cw + (size_t)cls * NF;
  const double* g0 = gfp + ((size_t)0 * NB + b) * NF;
  const double* g1 = gfp + ((size_t)1 * NB + b) * NF;
  const double* g2 = gfp + ((size_t)2 * NB + b) * NF;
  const double* g3 = gfp + ((size_t)3 * NB + b) * NF;
  double acc = 0.0;
#pragma unroll
  for (int k = 0; k < NF / 64; ++k) {
    const int f = k * 64 + lane;
    const double gv = (double)(float)((g0[f] + g1[f] + g2[f] + g3[f]) / 196.0);
    acc += (double)w[f] * gv;
  }
  acc = wave_reduce_f64(acc);
  if (lane == 0) gs_out[b * NC + cls] = sigmoidf_((float)(acc + (double)cb[cls]));
}

// ---------------- K2b: top-4 per batch via 4 rounds of butterfly arg-max (tie -> lowest index).
__global__ __launch_bounds__(64) void k2b_topk(
    const float* __restrict__ gs,   // d_out (8,80)
    int* __restrict__ topi)         // (8,4)
{
  const int b = blockIdx.x, lane = threadIdx.x;
  float v0 = gs[b * NC + lane];
  float v1 = (lane < NC - 64) ? gs[b * NC + 64 + lane] : -1e30f;
  const int i0 = lane, i1 = 64 + lane;
#pragma unroll
  for (int t = 0; t < TOPN; ++t) {
    float bv; int bi;
    if (v1 > v0) { bv = v1; bi = i1; } else { bv = v0; bi = i0; }
#pragma unroll
    for (int off = 1; off < 64; off <<= 1) {
      float ov = __shfl_xor(bv, off);
      int oi = __shfl_xor(bi, off);
      if (ov > bv || (ov == bv && oi < bi)) { bv = ov; bi = oi; }
    }
    if (lane == 0) topi[b * TOPN + t] = bi;
    if (bi == i0) v0 = -1e30f;
    if (bi == i1) v1 = -1e30f;
  }
}

// ---------------- K3a: cam dots — one wave per (bt, p). grid (49, 32), 256 threads (4 waves).
__global__ __launch_bounds__(256) void k3a_cam(
    const float* __restrict__ ga,   // (8,196,1280)
    const float* __restrict__ cw,
    const float* __restrict__ cb,
    const int* __restrict__ topi,
    float* __restrict__ camg)       // (32,196)
{
  const int pc = blockIdx.x, bt = blockIdx.y;
  const int tid = threadIdx.x, wid = tid >> 6, lane = tid & 63;
  const int p = pc * 4 + wid;
  const int b = bt >> 2;
  const int cls = topi[bt];
  const float* w = cw + (size_t)cls * NF;
  const float* g = ga + ((size_t)b * NP + p) * NF;
  double acc = 0.0;
#pragma unroll
  for (int k = 0; k < NF / 64; ++k) {
    const int f = k * 64 + lane;
    acc += (double)g[f] * (double)w[f];
  }
  acc = wave_reduce_f64(acc);
  if (lane == 0) camg[bt * NP + p] = sigmoidf_((float)(acc + (double)cb[cls]));
}

// ---------------- K3b: per bt: wscore/hscore via piecewise-linear segment-max
//                  -> minmax_norm + obj_loc -> integer bounds {y1,y2,x1,x2}
__global__ __launch_bounds__(256) void k3b_bounds(
    const float* __restrict__ camg, // (32,196)
    int* __restrict__ bounds)       // (32,4)
{
  __shared__ float cam[NP];
  __shared__ float wsS[HW];
  __shared__ float hsS[HW];
  __shared__ int jlo[OS], jhi[OS];
  const int bt = blockIdx.x, tid = threadIdx.x;
  const int wid = tid >> 6, lane = tid & 63;
  const float SC = 13.0f / 447.0f;

  if (tid < OS) { jlo[tid] = 1 << 30; jhi[tid] = -1; }
  for (int i = tid; i < NP; i += 256) cam[i] = camg[bt * NP + i];
  __syncthreads();
  // per-segment extreme sample indices (identical floor/clamp math as the reference sampling)
  for (int j = tid; j < HW; j += 256) {
    float yp = (float)j * SC;
    int y0 = (int)floorf(yp); if (y0 > 13) y0 = 13;
    atomicMin(&jlo[y0], j);
    atomicMax(&jhi[y0], j);
  }
  __syncthreads();

  // phase B: per output column/row, segment max (2 evals/segment)
  for (int x = tid; x < HW; x += 256) {
    float xp = (float)x * SC;
    int x0 = (int)floorf(xp); if (x0 > 13) x0 = 13;
    float wx = xp - (float)x0;
    int x1i = min(x0 + 1, 13);
    {
      float cv[OS];
#pragma unroll
      for (int r = 0; r < OS; ++r)
        cv[r] = cam[r * OS + x0] * (1.0f - wx) + cam[r * OS + x1i] * wx;
      float m = -1e30f;
#pragma unroll
      for (int r = 0; r < OS; ++r) {
        int jl = jlo[r], jh = jhi[r];
        if (jl <= jh) {
          const int rn = (r + 1 < OS) ? r + 1 : OS - 1;
          float yp1 = (float)jl * SC; float wy1 = yp1 - (float)r;
          float yp2 = (float)jh * SC; float wy2 = yp2 - (float)r;
          float v1 = cv[r] * (1.0f - wy1) + cv[rn] * wy1;
          float v2 = cv[r] * (1.0f - wy2) + cv[rn] * wy2;
          m = fmaxf(m, fmaxf(v1, v2));
        }
      }
      wsS[x] = m;
    }
    {
      float cv[OS];
#pragma unroll
      for (int c = 0; c < OS; ++c)
        cv[c] = cam[x0 * OS + c] * (1.0f - wx) + cam[x1i * OS + c] * wx;
      float m = -1e30f;
#pragma unroll
      for (int r = 0; r < OS; ++r) {
        int jl = jlo[r], jh = jhi[r];
        if (jl <= jh) {
          const int rn = (r + 1 < OS) ? r + 1 : OS - 1;
          float xp1 = (float)jl * SC; float w1 = xp1 - (float)r;
          float xp2 = (float)jh * SC; float w2 = xp2 - (float)r;
          float v1 = cv[r] * (1.0f - w1) + cv[rn] * w1;
          float v2 = cv[r] * (1.0f - w2) + cv[rn] * w2;
          m = fmaxf(m, fmaxf(v1, v2));
        }
      }
      hsS[x] = m;
    }
  }
  __syncthreads();

  // phase C: parallel minmax_norm + obj_loc. wave0 -> wscore(x), wave1 -> hscore(y)
  if (wid < 2) {
    const float* s = (wid == 0) ? wsS : hsS;
    float v[7];
    float mn = 1e30f, mx = -1e30f;
#pragma unroll
    for (int q = 0; q < 7; ++q) {
      v[q] = s[lane + 64 * q];
      mn = fminf(mn, v[q]); mx = fmaxf(mx, v[q]);
    }
#pragma unroll
    for (int off = 32; off > 0; off >>= 1) {
      mn = fminf(mn, __shfl_down(mn, off));
      mx = fmaxf(mx, __shfl_down(mx, off));
    }
    mn = __shfl(mn, 0); mx = __shfl(mx, 0);
    float rng = mx - mn;
    float dnm = (mx != 0.0f) ? mx : 1.0f;
    int firstL = 1 << 30, lastL = -1;
#pragma unroll
    for (int q = 0; q < 7; ++q) {
      float nv = (rng > 0.0f) ? (v[q] - mn) / rng : v[q] / dnm;
      if (nv >= 0.5f) {
        int idx = lane + 64 * q;
        firstL = min(firstL, idx);
        lastL = max(lastL, idx);
      }
    }
#pragma unroll
    for (int off = 32; off > 0; off >>= 1) {
      firstL = min(firstL, __shfl_down(firstL, off));
      lastL = max(lastL, __shfl_down(lastL, off));
    }
    if (lane == 0) {
      int lo, hi;
      if (lastL >= 0) { lo = firstL; hi = lastL + 1; }
      else { lo = 56; hi = 392; }             // int(448*0.125), int(448*0.875)
      int need = 56 - (hi - lo); if (need < 0) need = 0;
      int pad = (need + 1) >> 1;
      lo = lo - pad; if (lo < 0) lo = 0;
      hi = hi + pad; if (hi > HW) hi = HW;
      if (wid == 0) { bounds[bt * 4 + 2] = lo; bounds[bt * 4 + 3] = hi; }  // x1,x2
      else          { bounds[bt * 4 + 0] = lo; bounds[bt * 4 + 1] = hi; }  // y1,y2
    }
  }
}

// ---------------- K4: fused bilinear-crop + conv + clip, position-split 4x -> f64 partials lfp.
// grid (5, 32, 4): x = filter chunk, y = (b,t), z = 49-position chunk.
__global__ __launch_bounds__(256) void k4_conv_local(
    const float* __restrict__ in,
    const float* __restrict__ fw,
    const float* __restrict__ fb,
    const int* __restrict__ bounds,
    double* __restrict__ lfp)       // (4,32,1280) partial sums
{
  __shared__ float patch[PATCH];
  const int bt = blockIdx.y, fc = blockIdx.x, pz = blockIdx.z, tid = threadIdx.x;
  const int b = bt >> 2;
  const int y1 = bounds[bt * 4 + 0], y2 = bounds[bt * 4 + 1];
  const int x1 = bounds[bt * 4 + 2], x2 = bounds[bt * 4 + 3];
  const float y1f = (float)y1, x1f = (float)x1;
  const float sy = (float)(y2 - 1 - y1) / 447.0f;
  const float sx = (float)(x2 - 1 - x1) / 447.0f;
  const float* img = in + (size_t)b * 3 * HW * HW;
  for (int i = tid; i < PATCH; i += 256) {
    int c = i / 1764, rem = i % 1764, r = rem / 42, cc = rem % 42;
    int yy = 32 * (r / 3) + (r % 3) - 1;   // crop-space row (conv pad -> -1)
    int xx = 32 * (cc / 3) + (cc % 3) - 1;
    float v = 0.0f;
    if (yy >= 0 && xx >= 0) {
      float ys = y1f + (float)yy * sy;
      float xs = x1f + (float)xx * sx;
      float y0 = floorf(ys); if (y0 < 0.0f) y0 = 0.0f; if (y0 > 447.0f) y0 = 447.0f;
      float x0 = floorf(xs); if (x0 < 0.0f) x0 = 0.0f; if (x0 > 447.0f) x0 = 447.0f;
      int y0i = (int)y0, x0i = (int)x0;
      int y1i = min(y0i + 1, HW - 1), x1i = min(x0i + 1, HW - 1);
      float wy = ys - y0, wx = xs - x0;
      const float* ic = img + (size_t)c * HW * HW;
      float a  = ic[y0i * HW + x0i], bb = ic[y0i * HW + x1i];
      float cc2 = ic[y1i * HW + x0i], d  = ic[y1i * HW + x1i];
      float top = a * (1.0f - wx) + bb * wx;
      float bot = cc2 * (1.0f - wx) + d * wx;
      v = top * (1.0f - wy) + bot * wy;
    }
    patch[i] = v;
  }
  __syncthreads();
  const int f = fc * 256 + tid;
  float w[27];
#pragma unroll
  for (int k = 0; k < 27; ++k) w[k] = fw[f * 27 + k];
  const float bias = fb[f];
  double sum = 0.0;
#pragma unroll 7
  for (int pi = 0; pi < NPCH; ++pi) {
    const int p = pz * NPCH + pi;
    const int oy = p / OS, ox = p % OS;
    float acc = bias;
#pragma unroll
    for (int c = 0; c < 3; ++c)
#pragma unroll
      for (int ky = 0; ky < 3; ++ky)
#pragma unroll
        for (int kx = 0; kx < 3; ++kx)
          acc += patch[c * 1764 + (oy * 3 + ky) * 42 + (ox * 3 + kx)] * w[c * 9 + ky * 3 + kx];
    acc = fminf(fmaxf(acc, 0.0f), 6.0f);
    sum += (double)acc;
  }
  lfp[((size_t)pz * (NB * TOPN) + bt) * NF + f] = sum;
}

// ---------------- K5: ls = max over t of sigmoid(1x1 conv on lf). One wave per (b, cls).
// grid (80, 8), 64 threads. Combines the 4 f64 partials -> f32 lf inline.
__global__ __launch_bounds__(64) void k5_ls(
    const double* __restrict__ lfp, // (4,32,1280)
    const float* __restrict__ cw,
    const float* __restrict__ cb,
    float* __restrict__ ls_out)     // d_out + 640
{
  const int cls = blockIdx.x, b = blockIdx.y, lane = threadIdx.x;
  const float* w = cw + (size_t)cls * NF;
  double a0 = 0.0, a1 = 0.0, a2 = 0.0, a3 = 0.0;
#pragma unroll
  for (int k = 0; k < NF / 64; ++k) {
    const int f = k * 64 + lane;
    const double wv = (double)w[f];
    double lv[TOPN];
#pragma unroll
    for (int t = 0; t < TOPN; ++t) {
      const int bt = b * TOPN + t;
      lv[t] = (double)(float)((lfp[((size_t)0 * 32 + bt) * NF + f] +
                               lfp[((size_t)1 * 32 + bt) * NF + f] +
                               lfp[((size_t)2 * 32 + bt) * NF + f] +
                               lfp[((size_t)3 * 32 + bt) * NF + f]) / 196.0);
    }
    a0 += wv * lv[0];
    a1 += wv * lv[1];
    a2 += wv * lv[2];
    a3 += wv * lv[3];
  }
  a0 = wave_reduce_f64(a0);
  a1 = wave_reduce_f64(a1);
  a2 = wave_reduce_f64(a2);
  a3 = wave_reduce_f64(a3);
  if (lane == 0) {
    const double bias = (double)cb[cls];
    float m = sigmoidf_((float)(a0 + bias));
    m = fmaxf(m, sigmoidf_((float)(a1 + bias)));
    m = fmaxf(m, sigmoidf_((float)(a2 + bias)));
    m = fmaxf(m, sigmoidf_((float)(a3 + bias)));
    ls_out[b * NC + cls] = m;
  }
}

extern "C" void kernel_launch(void* const* d_in, const int* in_sizes, int n_in,
                              void* d_out, int out_size, void* d_ws, size_t ws_size,
                              hipStream_t stream) {
  const float* in = (const float*)d_in[0];   // (8,3,448,448)
  const float* fw = (const float*)d_in[1];   // (1280,3,3,3)
  const float* fb = (const float*)d_in[2];   // (1280)
  const float* cw = (const float*)d_in[3];   // (80,1280,1,1)
  const float* cb = (const float*)d_in[4];   // (80)
  float* out = (float*)d_out;                // gs(640) ++ ls(640)

  // ws layout (f64 arrays first for alignment): ~9.7 MB total
  double* gfp = (double*)d_ws;                         // 4*8*1280
  double* lfp = gfp + (size_t)4 * NB * NF;             // 4*32*1280
  float* ga = (float*)(lfp + (size_t)4 * NB * TOPN * NF); // 8*196*1280
  float* camg = ga + (size_t)NB * NP * NF;             // 32*196
  int* topi = (int*)(camg + NB * TOPN * NP);           // 32
  int* bounds = topi + NB * TOPN;                      // 128

  k1_conv_global<<<dim3(5, NB, 4), 256, 0, stream>>>(in, fw, fb, ga, gfp);
  k2a_gs<<<dim3(NC, NB), 64, 0, stream>>>(gfp, cw, cb, out);
  k2b_topk<<<NB, 64, 0, stream>>>(out, topi);
  k3a_cam<<<dim3(NPCH, NB * TOPN), 256, 0, stream>>>(ga, cw, cb, topi, camg);
  k3b_bounds<<<NB * TOPN, 256, 0, stream>>>(camg, bounds);
  k4_conv_local<<<dim3(5, NB * TOPN, 4), 256, 0, stream>>>(in, fw, fb, bounds, lfp);
  k5_ls<<<dim3(NC, NB), 64, 0, stream>>>(lfp, cw, cb, out + 640);
}

// Round 6
// 165.564 us; speedup vs baseline: 4.0137x; 1.3497x over previous
//
#include <hip/hip_runtime.h>
#include <math.h>

// Problem constants
#define NB 8           // batch
#define TOPN 4
#define NC 80          // classes
#define NF 1280        // features
#define HW 448         // image H=W
#define OS 14          // conv out spatial
#define NP 196         // OS*OS
#define NPCH 49        // positions per z-chunk (NP/4)
#define PATCH (3*42*42)

__device__ __forceinline__ float sigmoidf_(float x) { return 1.0f / (1.0f + expf(-x)); }

__device__ __forceinline__ double wave_reduce_f64(double v) {
#pragma unroll
  for (int off = 32; off > 0; off >>= 1) v += __shfl_down(v, off);
  return v;
}

// ---------------- K1: global conv (stride 32, pad 1, clip 0..6), position-split 4x.
// grid (5, 8, 4): x = filter chunk (256 filters), y = batch, z = 49-position chunk.
__global__ __launch_bounds__(256) void k1_conv_global(
    const float* __restrict__ in,   // (8,3,448,448)
    const float* __restrict__ fw,   // (1280,3,3,3) flat
    const float* __restrict__ fb,   // (1280)
    float* __restrict__ ga,         // (8,196,1280)
    double* __restrict__ gfp)       // (4,8,1280) partial sums
{
  __shared__ float patch[PATCH];
  const int b = blockIdx.y, fc = blockIdx.x, pz = blockIdx.z, tid = threadIdx.x;
  for (int i = tid; i < PATCH; i += 256) {
    int c = i / 1764, rem = i % 1764, r = rem / 42, cc = rem % 42;
    int row = 32 * (r / 3) + (r % 3) - 1;
    int col = 32 * (cc / 3) + (cc % 3) - 1;
    float v = 0.0f;
    if (row >= 0 && col >= 0)
      v = in[((b * 3 + c) * HW + row) * HW + col];
    patch[i] = v;
  }
  __syncthreads();
  const int f = fc * 256 + tid;
  float w[27];
#pragma unroll
  for (int k = 0; k < 27; ++k) w[k] = fw[f * 27 + k];
  const float bias = fb[f];
  double sum = 0.0;
#pragma unroll 7
  for (int pi = 0; pi < NPCH; ++pi) {
    const int p = pz * NPCH + pi;
    const int oy = p / OS, ox = p % OS;
    float acc = bias;
#pragma unroll
    for (int c = 0; c < 3; ++c)
#pragma unroll
      for (int ky = 0; ky < 3; ++ky)
#pragma unroll
        for (int kx = 0; kx < 3; ++kx)
          acc += patch[c * 1764 + (oy * 3 + ky) * 42 + (ox * 3 + kx)] * w[c * 9 + ky * 3 + kx];
    acc = fminf(fmaxf(acc, 0.0f), 6.0f);
    ga[((size_t)b * NP + p) * NF + f] = acc;
    sum += (double)acc;
  }
  gfp[((size_t)pz * NB + b) * NF + f] = sum;
}

// ---------------- K2a: gs = sigmoid(1x1 conv on gf). One wave per (b, cls).
__global__ __launch_bounds__(64) void k2a_gs(
    const double* __restrict__ gfp, // (4,8,1280)
    const float* __restrict__ cw,   // (80,1280)
    const float* __restrict__ cb,   // (80)
    float* __restrict__ gs_out)     // d_out (8,80)
{
  const int cls = blockIdx.x, b = blockIdx.y, lane = threadIdx.x;
  const float* w = cw + (size_t)cls * NF;
  const double* g0 = gfp + ((size_t)0 * NB + b) * NF;
  const double* g1 = gfp + ((size_t)1 * NB + b) * NF;
  const double* g2 = gfp + ((size_t)2 * NB + b) * NF;
  const double* g3 = gfp + ((size_t)3 * NB + b) * NF;
  double acc = 0.0;
#pragma unroll
  for (int k = 0; k < NF / 64; ++k) {
    const int f = k * 64 + lane;
    const double gv = (double)(float)((g0[f] + g1[f] + g2[f] + g3[f]) / 196.0);
    acc += (double)w[f] * gv;
  }
  acc = wave_reduce_f64(acc);
  if (lane == 0) gs_out[b * NC + cls] = sigmoidf_((float)(acc + (double)cb[cls]));
}

// ---------------- K2b: top-4 per batch via 4 rounds of butterfly arg-max (tie -> lowest index).
__global__ __launch_bounds__(64) void k2b_topk(
    const float* __restrict__ gs,   // d_out (8,80)
    int* __restrict__ topi)         // (8,4)
{
  const int b = blockIdx.x, lane = threadIdx.x;
  float v0 = gs[b * NC + lane];
  float v1 = (lane < NC - 64) ? gs[b * NC + 64 + lane] : -1e30f;
  const int i0 = lane, i1 = 64 + lane;
#pragma unroll
  for (int t = 0; t < TOPN; ++t) {
    float bv; int bi;
    if (v1 > v0) { bv = v1; bi = i1; } else { bv = v0; bi = i0; }
#pragma unroll
    for (int off = 1; off < 64; off <<= 1) {
      float ov = __shfl_xor(bv, off);
      int oi = __shfl_xor(bi, off);
      if (ov > bv || (ov == bv && oi < bi)) { bv = ov; bi = oi; }
    }
    if (lane == 0) topi[b * TOPN + t] = bi;
    if (bi == i0) v0 = -1e30f;
    if (bi == i1) v1 = -1e30f;
  }
}

// ---------------- K3a: cam dots — one wave per (bt, p). grid (49, 32), 256 threads (4 waves).
__global__ __launch_bounds__(256) void k3a_cam(
    const float* __restrict__ ga,   // (8,196,1280)
    const float* __restrict__ cw,
    const float* __restrict__ cb,
    const int* __restrict__ topi,
    float* __restrict__ camg)       // (32,196)
{
  const int pc = blockIdx.x, bt = blockIdx.y;
  const int tid = threadIdx.x, wid = tid >> 6, lane = tid & 63;
  const int p = pc * 4 + wid;
  const int b = bt >> 2;
  const int cls = topi[bt];
  const float* w = cw + (size_t)cls * NF;
  const float* g = ga + ((size_t)b * NP + p) * NF;
  double acc = 0.0;
#pragma unroll
  for (int k = 0; k < NF / 64; ++k) {
    const int f = k * 64 + lane;
    acc += (double)g[f] * (double)w[f];
  }
  acc = wave_reduce_f64(acc);
  if (lane == 0) camg[bt * NP + p] = sigmoidf_((float)(acc + (double)cb[cls]));
}

// ---------------- K3b: per bt: segment-max scores -> bounds -> FUSED bilinear crop-staging.
// One block per bt, 256 threads. Writes patchg[bt][5292] (the 42x42x3 crop sample grid).
__global__ __launch_bounds__(256) void k3b_bounds_stage(
    const float* __restrict__ camg, // (32,196)
    const float* __restrict__ in,   // (8,3,448,448)
    float* __restrict__ patchg)     // (32,5292)
{
  __shared__ float cam[NP];
  __shared__ float wsS[HW];
  __shared__ float hsS[HW];
  __shared__ int jlo[OS], jhi[OS];
  __shared__ int shb[4];            // y1,y2,x1,x2
  const int bt = blockIdx.x, tid = threadIdx.x;
  const int wid = tid >> 6, lane = tid & 63;
  const float SC = 13.0f / 447.0f;

  if (tid < OS) { jlo[tid] = 1 << 30; jhi[tid] = -1; }
  for (int i = tid; i < NP; i += 256) cam[i] = camg[bt * NP + i];
  __syncthreads();
  for (int j = tid; j < HW; j += 256) {
    float yp = (float)j * SC;
    int y0 = (int)floorf(yp); if (y0 > 13) y0 = 13;
    atomicMin(&jlo[y0], j);
    atomicMax(&jhi[y0], j);
  }
  __syncthreads();

  // phase B: per output column/row, piecewise-linear segment max (2 evals/segment)
  for (int x = tid; x < HW; x += 256) {
    float xp = (float)x * SC;
    int x0 = (int)floorf(xp); if (x0 > 13) x0 = 13;
    float wx = xp - (float)x0;
    int x1i = min(x0 + 1, 13);
    {
      float cv[OS];
#pragma unroll
      for (int r = 0; r < OS; ++r)
        cv[r] = cam[r * OS + x0] * (1.0f - wx) + cam[r * OS + x1i] * wx;
      float m = -1e30f;
#pragma unroll
      for (int r = 0; r < OS; ++r) {
        int jl = jlo[r], jh = jhi[r];
        if (jl <= jh) {
          const int rn = (r + 1 < OS) ? r + 1 : OS - 1;
          float yp1 = (float)jl * SC; float wy1 = yp1 - (float)r;
          float yp2 = (float)jh * SC; float wy2 = yp2 - (float)r;
          float v1 = cv[r] * (1.0f - wy1) + cv[rn] * wy1;
          float v2 = cv[r] * (1.0f - wy2) + cv[rn] * wy2;
          m = fmaxf(m, fmaxf(v1, v2));
        }
      }
      wsS[x] = m;
    }
    {
      float cv[OS];
#pragma unroll
      for (int c = 0; c < OS; ++c)
        cv[c] = cam[x0 * OS + c] * (1.0f - wx) + cam[x1i * OS + c] * wx;
      float m = -1e30f;
#pragma unroll
      for (int r = 0; r < OS; ++r) {
        int jl = jlo[r], jh = jhi[r];
        if (jl <= jh) {
          const int rn = (r + 1 < OS) ? r + 1 : OS - 1;
          float xp1 = (float)jl * SC; float w1 = xp1 - (float)r;
          float xp2 = (float)jh * SC; float w2 = xp2 - (float)r;
          float v1 = cv[r] * (1.0f - w1) + cv[rn] * w1;
          float v2 = cv[r] * (1.0f - w2) + cv[rn] * w2;
          m = fmaxf(m, fmaxf(v1, v2));
        }
      }
      hsS[x] = m;
    }
  }
  __syncthreads();

  // phase C: parallel minmax_norm + obj_loc. wave0 -> wscore(x), wave1 -> hscore(y)
  if (wid < 2) {
    const float* s = (wid == 0) ? wsS : hsS;
    float v[7];
    float mn = 1e30f, mx = -1e30f;
#pragma unroll
    for (int q = 0; q < 7; ++q) {
      v[q] = s[lane + 64 * q];
      mn = fminf(mn, v[q]); mx = fmaxf(mx, v[q]);
    }
#pragma unroll
    for (int off = 32; off > 0; off >>= 1) {
      mn = fminf(mn, __shfl_down(mn, off));
      mx = fmaxf(mx, __shfl_down(mx, off));
    }
    mn = __shfl(mn, 0); mx = __shfl(mx, 0);
    float rng = mx - mn;
    float dnm = (mx != 0.0f) ? mx : 1.0f;
    int firstL = 1 << 30, lastL = -1;
#pragma unroll
    for (int q = 0; q < 7; ++q) {
      float nv = (rng > 0.0f) ? (v[q] - mn) / rng : v[q] / dnm;
      if (nv >= 0.5f) {
        int idx = lane + 64 * q;
        firstL = min(firstL, idx);
        lastL = max(lastL, idx);
      }
    }
#pragma unroll
    for (int off = 32; off > 0; off >>= 1) {
      firstL = min(firstL, __shfl_down(firstL, off));
      lastL = max(lastL, __shfl_down(lastL, off));
    }
    if (lane == 0) {
      int lo, hi;
      if (lastL >= 0) { lo = firstL; hi = lastL + 1; }
      else { lo = 56; hi = 392; }             // int(448*0.125), int(448*0.875)
      int need = 56 - (hi - lo); if (need < 0) need = 0;
      int pad = (need + 1) >> 1;
      lo = lo - pad; if (lo < 0) lo = 0;
      hi = hi + pad; if (hi > HW) hi = HW;
      if (wid == 0) { shb[2] = lo; shb[3] = hi; }  // x1,x2
      else          { shb[0] = lo; shb[1] = hi; }  // y1,y2
    }
  }
  __syncthreads();

  // phase D: fused bilinear crop-sample of the 42x42x3 conv input grid -> patchg[bt]
  const int b = bt >> 2;
  const int y1 = shb[0], y2 = shb[1], x1 = shb[2], x2 = shb[3];
  const float y1f = (float)y1, x1f = (float)x1;
  const float sy = (float)(y2 - 1 - y1) / 447.0f;
  const float sx = (float)(x2 - 1 - x1) / 447.0f;
  const float* img = in + (size_t)b * 3 * HW * HW;
  for (int i = tid; i < PATCH; i += 256) {
    int c = i / 1764, rem = i % 1764, r = rem / 42, cc = rem % 42;
    int yy = 32 * (r / 3) + (r % 3) - 1;   // crop-space row (conv pad -> -1)
    int xx = 32 * (cc / 3) + (cc % 3) - 1;
    float v = 0.0f;
    if (yy >= 0 && xx >= 0) {
      float ys = y1f + (float)yy * sy;
      float xs = x1f + (float)xx * sx;
      float y0 = floorf(ys); if (y0 < 0.0f) y0 = 0.0f; if (y0 > 447.0f) y0 = 447.0f;
      float x0 = floorf(xs); if (x0 < 0.0f) x0 = 0.0f; if (x0 > 447.0f) x0 = 447.0f;
      int y0i = (int)y0, x0i = (int)x0;
      int y1i = min(y0i + 1, HW - 1), x1i = min(x0i + 1, HW - 1);
      float wy = ys - y0, wx = xs - x0;
      const float* ic = img + (size_t)c * HW * HW;
      float a  = ic[y0i * HW + x0i], bb = ic[y0i * HW + x1i];
      float cc2 = ic[y1i * HW + x0i], d  = ic[y1i * HW + x1i];
      float top = a * (1.0f - wx) + bb * wx;
      float bot = cc2 * (1.0f - wx) + d * wx;
      v = top * (1.0f - wy) + bot * wy;
    }
    patchg[(size_t)bt * PATCH + i] = v;
  }
}

// ---------------- K4: local conv on pre-staged crop patches, position-split 4x -> f64 partials.
// grid (5, 32, 4): x = filter chunk, y = (b,t), z = 49-position chunk. LDS staged coalesced.
__global__ __launch_bounds__(256) void k4_conv_local(
    const float* __restrict__ patchg, // (32,5292)
    const float* __restrict__ fw,
    const float* __restrict__ fb,
    double* __restrict__ lfp)       // (4,32,1280) partial sums
{
  __shared__ float patch[PATCH];
  const int bt = blockIdx.y, fc = blockIdx.x, pz = blockIdx.z, tid = threadIdx.x;
  for (int i = tid; i < PATCH; i += 256)
    patch[i] = patchg[(size_t)bt * PATCH + i];
  __syncthreads();
  const int f = fc * 256 + tid;
  float w[27];
#pragma unroll
  for (int k = 0; k < 27; ++k) w[k] = fw[f * 27 + k];
  const float bias = fb[f];
  double sum = 0.0;
#pragma unroll 7
  for (int pi = 0; pi < NPCH; ++pi) {
    const int p = pz * NPCH + pi;
    const int oy = p / OS, ox = p % OS;
    float acc = bias;
#pragma unroll
    for (int c = 0; c < 3; ++c)
#pragma unroll
      for (int ky = 0; ky < 3; ++ky)
#pragma unroll
        for (int kx = 0; kx < 3; ++kx)
          acc += patch[c * 1764 + (oy * 3 + ky) * 42 + (ox * 3 + kx)] * w[c * 9 + ky * 3 + kx];
    acc = fminf(fmaxf(acc, 0.0f), 6.0f);
    sum += (double)acc;
  }
  lfp[((size_t)pz * (NB * TOPN) + bt) * NF + f] = sum;
}

// ---------------- Kcomb: lf32[bt][f] = (float)((p0+p1+p2+p3)/196.0)  (bitwise = old inline combine)
__global__ __launch_bounds__(256) void kcomb_lf(
    const double* __restrict__ lfp, // (4,32,1280)
    float* __restrict__ lf32)       // (32,1280)
{
  const int j = blockIdx.x * 256 + threadIdx.x;   // 0 .. 40959
  const double s = lfp[j] + lfp[40960 + j] + lfp[81920 + j] + lfp[122880 + j];
  lf32[j] = (float)(s / 196.0);
}

// ---------------- K5: ls = max over t of sigmoid(1x1 conv on lf32). One wave per (b, cls).
__global__ __launch_bounds__(64) void k5_ls(
    const float* __restrict__ lf32, // (32,1280)
    const float* __restrict__ cw,
    const float* __restrict__ cb,
    float* __restrict__ ls_out)     // d_out + 640
{
  const int cls = blockIdx.x, b = blockIdx.y, lane = threadIdx.x;
  const float* w = cw + (size_t)cls * NF;
  const float* l0 = lf32 + (size_t)(b * TOPN + 0) * NF;
  const float* l1 = lf32 + (size_t)(b * TOPN + 1) * NF;
  const float* l2 = lf32 + (size_t)(b * TOPN + 2) * NF;
  const float* l3 = lf32 + (size_t)(b * TOPN + 3) * NF;
  double a0 = 0.0, a1 = 0.0, a2 = 0.0, a3 = 0.0;
#pragma unroll
  for (int k = 0; k < NF / 64; ++k) {
    const int f = k * 64 + lane;
    const double wv = (double)w[f];
    a0 += wv * (double)l0[f];
    a1 += wv * (double)l1[f];
    a2 += wv * (double)l2[f];
    a3 += wv * (double)l3[f];
  }
  a0 = wave_reduce_f64(a0);
  a1 = wave_reduce_f64(a1);
  a2 = wave_reduce_f64(a2);
  a3 = wave_reduce_f64(a3);
  if (lane == 0) {
    const double bias = (double)cb[cls];
    float m = sigmoidf_((float)(a0 + bias));
    m = fmaxf(m, sigmoidf_((float)(a1 + bias)));
    m = fmaxf(m, sigmoidf_((float)(a2 + bias)));
    m = fmaxf(m, sigmoidf_((float)(a3 + bias)));
    ls_out[b * NC + cls] = m;
  }
}

extern "C" void kernel_launch(void* const* d_in, const int* in_sizes, int n_in,
                              void* d_out, int out_size, void* d_ws, size_t ws_size,
                              hipStream_t stream) {
  const float* in = (const float*)d_in[0];   // (8,3,448,448)
  const float* fw = (const float*)d_in[1];   // (1280,3,3,3)
  const float* fb = (const float*)d_in[2];   // (1280)
  const float* cw = (const float*)d_in[3];   // (80,1280,1,1)
  const float* cb = (const float*)d_in[4];   // (80)
  float* out = (float*)d_out;                // gs(640) ++ ls(640)

  // ws layout (f64 arrays first for alignment): ~10.2 MB total
  double* gfp = (double*)d_ws;                         // 4*8*1280
  double* lfp = gfp + (size_t)4 * NB * NF;             // 4*32*1280
  float* ga = (float*)(lfp + (size_t)4 * NB * TOPN * NF); // 8*196*1280
  float* lf32 = ga + (size_t)NB * NP * NF;             // 32*1280
  float* patchg = lf32 + (size_t)NB * TOPN * NF;       // 32*5292
  float* camg = patchg + (size_t)NB * TOPN * PATCH;    // 32*196
  int* topi = (int*)(camg + NB * TOPN * NP);           // 32

  k1_conv_global<<<dim3(5, NB, 4), 256, 0, stream>>>(in, fw, fb, ga, gfp);
  k2a_gs<<<dim3(NC, NB), 64, 0, stream>>>(gfp, cw, cb, out);
  k2b_topk<<<NB, 64, 0, stream>>>(out, topi);
  k3a_cam<<<dim3(NPCH, NB * TOPN), 256, 0, stream>>>(ga, cw, cb, topi, camg);
  k3b_bounds_stage<<<NB * TOPN, 256, 0, stream>>>(camg, in, patchg);
  k4_conv_local<<<dim3(5, NB * TOPN, 4), 256, 0, stream>>>(patchg, fw, fb, lfp);
  kcomb_lf<<<NB * TOPN * NF / 256, 256, 0, stream>>>(lfp, lf32);
  k5_ls<<<dim3(NC, NB), 64, 0, stream>>>(lf32, cw, cb, out + 640);
}

// Round 7
// 144.292 us; speedup vs baseline: 4.6055x; 1.1474x over previous
//
#include <hip/hip_runtime.h>
#include <math.h>

// Problem constants
#define NB 8           // batch
#define TOPN 4
#define NC 80          // classes
#define NF 1280        // features
#define HW 448         // image H=W
#define OS 14          // conv out spatial
#define NP 196         // OS*OS
#define PATCH (3*42*42)   // full 42x42x3 crop sample grid (k3b output)
#define ROWPATCH (3*3*42) // one output-row's input grid: 3 ch x 3 rows x 42 cols
#define WLDS (256*27)     // per-chunk filter weights staged in LDS

__device__ __forceinline__ float sigmoidf_(float x) { return 1.0f / (1.0f + expf(-x)); }

__device__ __forceinline__ double wave_reduce_f64(double v) {
#pragma unroll
  for (int off = 32; off > 0; off >>= 1) v += __shfl_down(v, off);
  return v;
}

// ---------------- K1: global conv (stride 32, pad 1, clip 0..6), row-split 14x.
// grid (5, 8, 14): x = filter chunk (256 filters), y = batch, z = output row oy.
// Stages 378 input samples + 6912 weights (coalesced) in LDS; 14 positions/thread.
__global__ __launch_bounds__(256) void k1_conv_global(
    const float* __restrict__ in,   // (8,3,448,448)
    const float* __restrict__ fw,   // (1280,3,3,3) flat
    const float* __restrict__ fb,   // (1280)
    float* __restrict__ ga,         // (8,196,1280)
    double* __restrict__ gfp)       // (14,8,1280) per-row partial sums
{
  __shared__ float patch[ROWPATCH];   // [c][rr][cc] : c*126 + rr*42 + cc
  __shared__ float wlds[WLDS];
  const int b = blockIdx.y, fc = blockIdx.x, oy = blockIdx.z, tid = threadIdx.x;
  // stage weights coalesced
  for (int i = tid; i < WLDS; i += 256) wlds[i] = fw[fc * WLDS + i];
  // stage this output-row's 3x42x3 input samples (row = 32*oy + rr - 1, zero-pad)
  for (int i = tid; i < ROWPATCH; i += 256) {
    int c = i / 126, rem = i % 126, rr = rem / 42, cc = rem % 42;
    int row = 32 * oy + rr - 1;
    int col = 32 * (cc / 3) + (cc % 3) - 1;
    float v = 0.0f;
    if (row >= 0 && col >= 0)
      v = in[((b * 3 + c) * HW + row) * HW + col];
    patch[i] = v;
  }
  __syncthreads();
  const int f = fc * 256 + tid;
  float w[27];
#pragma unroll
  for (int k = 0; k < 27; ++k) w[k] = wlds[tid * 27 + k];
  const float bias = fb[f];
  double sum = 0.0;
#pragma unroll 7
  for (int ox = 0; ox < OS; ++ox) {
    float acc = bias;
#pragma unroll
    for (int c = 0; c < 3; ++c)
#pragma unroll
      for (int ky = 0; ky < 3; ++ky)
#pragma unroll
        for (int kx = 0; kx < 3; ++kx)
          acc += patch[c * 126 + ky * 42 + ox * 3 + kx] * w[c * 9 + ky * 3 + kx];
    acc = fminf(fmaxf(acc, 0.0f), 6.0f);
    ga[((size_t)b * NP + oy * OS + ox) * NF + f] = acc;
    sum += (double)acc;
  }
  gfp[((size_t)oy * NB + b) * NF + f] = sum;
}

// ---------------- K2: gs = sigmoid(1x1 conv on gf) + top-4, one 1024-thread block per batch.
__global__ __launch_bounds__(1024) void k2_gs_topk(
    const double* __restrict__ gfp, // (14,8,1280)
    const float* __restrict__ cw,   // (80,1280)
    const float* __restrict__ cb,   // (80)
    float* __restrict__ gs_out,     // d_out (8,80)
    int* __restrict__ topi)         // (8,4)
{
  __shared__ float gfs[NF];
  __shared__ float gsv[NC];
  const int b = blockIdx.x, tid = threadIdx.x;
  // combine the 14 deterministic f64 row-partials -> f32 gf
  for (int i = tid; i < NF; i += 1024) {
    double s = 0.0;
#pragma unroll
    for (int z = 0; z < OS; ++z) s += gfp[((size_t)z * NB + b) * NF + i];
    gfs[i] = (float)(s / 196.0);
  }
  __syncthreads();
  const int wid = tid >> 6, lane = tid & 63;
  // 16 waves x 5 classes
  for (int j = 0; j < 5; ++j) {
    const int cls = wid * 5 + j;
    const float* w = cw + (size_t)cls * NF;
    double acc = 0.0;
#pragma unroll
    for (int k = 0; k < NF / 64; ++k) {
      int f = k * 64 + lane;
      acc += (double)w[f] * (double)gfs[f];
    }
    acc = wave_reduce_f64(acc);
    if (lane == 0) {
      float s = sigmoidf_((float)(acc + (double)cb[cls]));
      gsv[cls] = s;
      gs_out[b * NC + cls] = s;
    }
  }
  __syncthreads();
  // wave 0: 4 rounds of butterfly arg-max (tie -> lowest index)
  if (wid == 0) {
    float v0 = gsv[lane];
    float v1 = (lane < NC - 64) ? gsv[64 + lane] : -1e30f;
    const int i0 = lane, i1 = 64 + lane;
#pragma unroll
    for (int t = 0; t < TOPN; ++t) {
      float bv; int bi;
      if (v1 > v0) { bv = v1; bi = i1; } else { bv = v0; bi = i0; }
#pragma unroll
      for (int off = 1; off < 64; off <<= 1) {
        float ov = __shfl_xor(bv, off);
        int oi = __shfl_xor(bi, off);
        if (ov > bv || (ov == bv && oi < bi)) { bv = ov; bi = oi; }
      }
      if (lane == 0) topi[b * TOPN + t] = bi;
      if (bi == i0) v0 = -1e30f;
      if (bi == i1) v1 = -1e30f;
    }
  }
}

// ---------------- K3a: cam dots — one wave per (bt, p); clsw staged in LDS per block.
__global__ __launch_bounds__(256) void k3a_cam(
    const float* __restrict__ ga,   // (8,196,1280)
    const float* __restrict__ cw,
    const float* __restrict__ cb,
    const int* __restrict__ topi,
    float* __restrict__ camg)       // (32,196)
{
  __shared__ float clsw[NF];
  const int pc = blockIdx.x, bt = blockIdx.y;
  const int tid = threadIdx.x, wid = tid >> 6, lane = tid & 63;
  const int p = pc * 4 + wid;
  const int b = bt >> 2;
  const int cls = topi[bt];
  for (int i = tid; i < NF; i += 256) clsw[i] = cw[(size_t)cls * NF + i];
  __syncthreads();
  const float* g = ga + ((size_t)b * NP + p) * NF;
  double acc = 0.0;
#pragma unroll
  for (int k = 0; k < NF / 64; ++k) {
    const int f = k * 64 + lane;
    acc += (double)g[f] * (double)clsw[f];
  }
  acc = wave_reduce_f64(acc);
  if (lane == 0) camg[bt * NP + p] = sigmoidf_((float)(acc + (double)cb[cls]));
}

// ---------------- K3b: per bt: segment-max scores -> bounds -> FUSED bilinear crop-staging.
__global__ __launch_bounds__(256) void k3b_bounds_stage(
    const float* __restrict__ camg, // (32,196)
    const float* __restrict__ in,   // (8,3,448,448)
    float* __restrict__ patchg)     // (32,5292)
{
  __shared__ float cam[NP];
  __shared__ float wsS[HW];
  __shared__ float hsS[HW];
  __shared__ int jlo[OS], jhi[OS];
  __shared__ int shb[4];            // y1,y2,x1,x2
  const int bt = blockIdx.x, tid = threadIdx.x;
  const int wid = tid >> 6, lane = tid & 63;
  const float SC = 13.0f / 447.0f;

  if (tid < OS) { jlo[tid] = 1 << 30; jhi[tid] = -1; }
  for (int i = tid; i < NP; i += 256) cam[i] = camg[bt * NP + i];
  __syncthreads();
  for (int j = tid; j < HW; j += 256) {
    float yp = (float)j * SC;
    int y0 = (int)floorf(yp); if (y0 > 13) y0 = 13;
    atomicMin(&jlo[y0], j);
    atomicMax(&jhi[y0], j);
  }
  __syncthreads();

  // phase B: per output column/row, piecewise-linear segment max (2 evals/segment)
  for (int x = tid; x < HW; x += 256) {
    float xp = (float)x * SC;
    int x0 = (int)floorf(xp); if (x0 > 13) x0 = 13;
    float wx = xp - (float)x0;
    int x1i = min(x0 + 1, 13);
    {
      float cv[OS];
#pragma unroll
      for (int r = 0; r < OS; ++r)
        cv[r] = cam[r * OS + x0] * (1.0f - wx) + cam[r * OS + x1i] * wx;
      float m = -1e30f;
#pragma unroll
      for (int r = 0; r < OS; ++r) {
        int jl = jlo[r], jh = jhi[r];
        if (jl <= jh) {
          const int rn = (r + 1 < OS) ? r + 1 : OS - 1;
          float yp1 = (float)jl * SC; float wy1 = yp1 - (float)r;
          float yp2 = (float)jh * SC; float wy2 = yp2 - (float)r;
          float v1 = cv[r] * (1.0f - wy1) + cv[rn] * wy1;
          float v2 = cv[r] * (1.0f - wy2) + cv[rn] * wy2;
          m = fmaxf(m, fmaxf(v1, v2));
        }
      }
      wsS[x] = m;
    }
    {
      float cv[OS];
#pragma unroll
      for (int c = 0; c < OS; ++c)
        cv[c] = cam[x0 * OS + c] * (1.0f - wx) + cam[x1i * OS + c] * wx;
      float m = -1e30f;
#pragma unroll
      for (int r = 0; r < OS; ++r) {
        int jl = jlo[r], jh = jhi[r];
        if (jl <= jh) {
          const int rn = (r + 1 < OS) ? r + 1 : OS - 1;
          float xp1 = (float)jl * SC; float w1 = xp1 - (float)r;
          float xp2 = (float)jh * SC; float w2 = xp2 - (float)r;
          float v1 = cv[r] * (1.0f - w1) + cv[rn] * w1;
          float v2 = cv[r] * (1.0f - w2) + cv[rn] * w2;
          m = fmaxf(m, fmaxf(v1, v2));
        }
      }
      hsS[x] = m;
    }
  }
  __syncthreads();

  // phase C: parallel minmax_norm + obj_loc. wave0 -> wscore(x), wave1 -> hscore(y)
  if (wid < 2) {
    const float* s = (wid == 0) ? wsS : hsS;
    float v[7];
    float mn = 1e30f, mx = -1e30f;
#pragma unroll
    for (int q = 0; q < 7; ++q) {
      v[q] = s[lane + 64 * q];
      mn = fminf(mn, v[q]); mx = fmaxf(mx, v[q]);
    }
#pragma unroll
    for (int off = 32; off > 0; off >>= 1) {
      mn = fminf(mn, __shfl_down(mn, off));
      mx = fmaxf(mx, __shfl_down(mx, off));
    }
    mn = __shfl(mn, 0); mx = __shfl(mx, 0);
    float rng = mx - mn;
    float dnm = (mx != 0.0f) ? mx : 1.0f;
    int firstL = 1 << 30, lastL = -1;
#pragma unroll
    for (int q = 0; q < 7; ++q) {
      float nv = (rng > 0.0f) ? (v[q] - mn) / rng : v[q] / dnm;
      if (nv >= 0.5f) {
        int idx = lane + 64 * q;
        firstL = min(firstL, idx);
        lastL = max(lastL, idx);
      }
    }
#pragma unroll
    for (int off = 32; off > 0; off >>= 1) {
      firstL = min(firstL, __shfl_down(firstL, off));
      lastL = max(lastL, __shfl_down(lastL, off));
    }
    if (lane == 0) {
      int lo, hi;
      if (lastL >= 0) { lo = firstL; hi = lastL + 1; }
      else { lo = 56; hi = 392; }             // int(448*0.125), int(448*0.875)
      int need = 56 - (hi - lo); if (need < 0) need = 0;
      int pad = (need + 1) >> 1;
      lo = lo - pad; if (lo < 0) lo = 0;
      hi = hi + pad; if (hi > HW) hi = HW;
      if (wid == 0) { shb[2] = lo; shb[3] = hi; }  // x1,x2
      else          { shb[0] = lo; shb[1] = hi; }  // y1,y2
    }
  }
  __syncthreads();

  // phase D: fused bilinear crop-sample of the 42x42x3 conv input grid -> patchg[bt]
  const int b = bt >> 2;
  const int y1 = shb[0], y2 = shb[1], x1 = shb[2], x2 = shb[3];
  const float y1f = (float)y1, x1f = (float)x1;
  const float sy = (float)(y2 - 1 - y1) / 447.0f;
  const float sx = (float)(x2 - 1 - x1) / 447.0f;
  const float* img = in + (size_t)b * 3 * HW * HW;
  for (int i = tid; i < PATCH; i += 256) {
    int c = i / 1764, rem = i % 1764, r = rem / 42, cc = rem % 42;
    int yy = 32 * (r / 3) + (r % 3) - 1;   // crop-space row (conv pad -> -1)
    int xx = 32 * (cc / 3) + (cc % 3) - 1;
    float v = 0.0f;
    if (yy >= 0 && xx >= 0) {
      float ys = y1f + (float)yy * sy;
      float xs = x1f + (float)xx * sx;
      float y0 = floorf(ys); if (y0 < 0.0f) y0 = 0.0f; if (y0 > 447.0f) y0 = 447.0f;
      float x0 = floorf(xs); if (x0 < 0.0f) x0 = 0.0f; if (x0 > 447.0f) x0 = 447.0f;
      int y0i = (int)y0, x0i = (int)x0;
      int y1i = min(y0i + 1, HW - 1), x1i = min(x0i + 1, HW - 1);
      float wy = ys - y0, wx = xs - x0;
      const float* ic = img + (size_t)c * HW * HW;
      float a  = ic[y0i * HW + x0i], bb = ic[y0i * HW + x1i];
      float cc2 = ic[y1i * HW + x0i], d  = ic[y1i * HW + x1i];
      float top = a * (1.0f - wx) + bb * wx;
      float bot = cc2 * (1.0f - wx) + d * wx;
      v = top * (1.0f - wy) + bot * wy;
    }
    patchg[(size_t)bt * PATCH + i] = v;
  }
}

// ---------------- K4: local conv on pre-staged crop patches, row-split 14x.
// grid (5, 32, 14). Stages 378 patch floats + 6912 weights coalesced in LDS.
__global__ __launch_bounds__(256) void k4_conv_local(
    const float* __restrict__ patchg, // (32,5292)
    const float* __restrict__ fw,
    const float* __restrict__ fb,
    double* __restrict__ lfp)       // (14,32,1280) per-row partial sums
{
  __shared__ float patch[ROWPATCH];
  __shared__ float wlds[WLDS];
  const int bt = blockIdx.y, fc = blockIdx.x, oy = blockIdx.z, tid = threadIdx.x;
  for (int i = tid; i < WLDS; i += 256) wlds[i] = fw[fc * WLDS + i];
  for (int i = tid; i < ROWPATCH; i += 256) {
    int c = i / 126, rem = i % 126, rr = rem / 42, cc = rem % 42;
    patch[i] = patchg[(size_t)bt * PATCH + c * 1764 + (3 * oy + rr) * 42 + cc];
  }
  __syncthreads();
  const int f = fc * 256 + tid;
  float w[27];
#pragma unroll
  for (int k = 0; k < 27; ++k) w[k] = wlds[tid * 27 + k];
  const float bias = fb[f];
  double sum = 0.0;
#pragma unroll 7
  for (int ox = 0; ox < OS; ++ox) {
    float acc = bias;
#pragma unroll
    for (int c = 0; c < 3; ++c)
#pragma unroll
      for (int ky = 0; ky < 3; ++ky)
#pragma unroll
        for (int kx = 0; kx < 3; ++kx)
          acc += patch[c * 126 + ky * 42 + ox * 3 + kx] * w[c * 9 + ky * 3 + kx];
    acc = fminf(fmaxf(acc, 0.0f), 6.0f);
    sum += (double)acc;
  }
  lfp[((size_t)oy * (NB * TOPN) + bt) * NF + f] = sum;
}

// ---------------- Kcomb: lf32[bt][f] = (float)(sum_z lfp[z][bt][f] / 196.0)
__global__ __launch_bounds__(256) void kcomb_lf(
    const double* __restrict__ lfp, // (14,32,1280)
    float* __restrict__ lf32)       // (32,1280)
{
  const int j = blockIdx.x * 256 + threadIdx.x;   // 0 .. 40959
  double s = 0.0;
#pragma unroll
  for (int z = 0; z < OS; ++z) s += lfp[(size_t)z * 40960 + j];
  lf32[j] = (float)(s / 196.0);
}

// ---------------- K5: ls = max over t of sigmoid(1x1 conv on lf32). One wave per (b, cls).
__global__ __launch_bounds__(64) void k5_ls(
    const float* __restrict__ lf32, // (32,1280)
    const float* __restrict__ cw,
    const float* __restrict__ cb,
    float* __restrict__ ls_out)     // d_out + 640
{
  const int cls = blockIdx.x, b = blockIdx.y, lane = threadIdx.x;
  const float* w = cw + (size_t)cls * NF;
  const float* l0 = lf32 + (size_t)(b * TOPN + 0) * NF;
  const float* l1 = lf32 + (size_t)(b * TOPN + 1) * NF;
  const float* l2 = lf32 + (size_t)(b * TOPN + 2) * NF;
  const float* l3 = lf32 + (size_t)(b * TOPN + 3) * NF;
  double a0 = 0.0, a1 = 0.0, a2 = 0.0, a3 = 0.0;
#pragma unroll
  for (int k = 0; k < NF / 64; ++k) {
    const int f = k * 64 + lane;
    const double wv = (double)w[f];
    a0 += wv * (double)l0[f];
    a1 += wv * (double)l1[f];
    a2 += wv * (double)l2[f];
    a3 += wv * (double)l3[f];
  }
  a0 = wave_reduce_f64(a0);
  a1 = wave_reduce_f64(a1);
  a2 = wave_reduce_f64(a2);
  a3 = wave_reduce_f64(a3);
  if (lane == 0) {
    const double bias = (double)cb[cls];
    float m = sigmoidf_((float)(a0 + bias));
    m = fmaxf(m, sigmoidf_((float)(a1 + bias)));
    m = fmaxf(m, sigmoidf_((float)(a2 + bias)));
    m = fmaxf(m, sigmoidf_((float)(a3 + bias)));
    ls_out[b * NC + cls] = m;
  }
}

extern "C" void kernel_launch(void* const* d_in, const int* in_sizes, int n_in,
                              void* d_out, int out_size, void* d_ws, size_t ws_size,
                              hipStream_t stream) {
  const float* in = (const float*)d_in[0];   // (8,3,448,448)
  const float* fw = (const float*)d_in[1];   // (1280,3,3,3)
  const float* fb = (const float*)d_in[2];   // (1280)
  const float* cw = (const float*)d_in[3];   // (80,1280,1,1)
  const float* cb = (const float*)d_in[4];   // (80)
  float* out = (float*)d_out;                // gs(640) ++ ls(640)

  // ws layout (f64 arrays first for alignment): ~15 MB total
  double* gfp = (double*)d_ws;                            // 14*8*1280
  double* lfp = gfp + (size_t)OS * NB * NF;               // 14*32*1280
  float* ga = (float*)(lfp + (size_t)OS * NB * TOPN * NF);// 8*196*1280
  float* lf32 = ga + (size_t)NB * NP * NF;                // 32*1280
  float* patchg = lf32 + (size_t)NB * TOPN * NF;          // 32*5292
  float* camg = patchg + (size_t)NB * TOPN * PATCH;       // 32*196
  int* topi = (int*)(camg + NB * TOPN * NP);              // 32

  k1_conv_global<<<dim3(5, NB, OS), 256, 0, stream>>>(in, fw, fb, ga, gfp);
  k2_gs_topk<<<NB, 1024, 0, stream>>>(gfp, cw, cb, out, topi);
  k3a_cam<<<dim3(NP / 4, NB * TOPN), 256, 0, stream>>>(ga, cw, cb, topi, camg);
  k3b_bounds_stage<<<NB * TOPN, 256, 0, stream>>>(camg, in, patchg);
  k4_conv_local<<<dim3(5, NB * TOPN, OS), 256, 0, stream>>>(patchg, fw, fb, lfp);
  kcomb_lf<<<NB * TOPN * NF / 256, 256, 0, stream>>>(lfp, lf32);
  k5_ls<<<dim3(NC, NB), 64, 0, stream>>>(lf32, cw, cb, out + 640);
}